// Round 8
// baseline (742.538 us; speedup 1.0000x reference)
//
#include <hip/hip_runtime.h>
#include <cstdint>

#define B_ 2
#define S_ 2048
#define D_ 1024
#define H_ 16
#define DH_ 64
#define FF_ 4096
#define M_TOK (B_ * S_)  // 4096 token rows

typedef __attribute__((ext_vector_type(8))) short short8;
typedef __attribute__((ext_vector_type(4))) float f32x4;
typedef __attribute__((ext_vector_type(4))) unsigned short us4;

typedef unsigned short u16;

__device__ __forceinline__ float bf2f(u16 u) {
  union { uint32_t u; float f; } x;
  x.u = ((uint32_t)u) << 16;
  return x.f;
}
__device__ __forceinline__ u16 f2bf(float f) {
  union { float f; uint32_t u; } x;
  x.f = f;
  uint32_t r = x.u + 0x7FFFu + ((x.u >> 16) & 1u);  // RNE
  return (u16)(r >> 16);
}
// convert 8 contiguous f32 -> short8 (bf16 bits)
__device__ __forceinline__ short8 cvt8(const float* p) {
  const float4 a = *(const float4*)p;
  const float4 b = *(const float4*)(p + 4);
  short8 r;
  r[0] = (short)f2bf(a.x); r[1] = (short)f2bf(a.y);
  r[2] = (short)f2bf(a.z); r[3] = (short)f2bf(a.w);
  r[4] = (short)f2bf(b.x); r[5] = (short)f2bf(b.y);
  r[6] = (short)f2bf(b.z); r[7] = (short)f2bf(b.w);
  return r;
}

// ---------------- RMSNorm: one block per token row (f32 in, bf16 out) ----------------
__global__ __launch_bounds__(256) void rmsnorm_k(const float* __restrict__ X,
                                                 const float* __restrict__ G,
                                                 u16* __restrict__ Hout) {
  const int row = blockIdx.x;
  const int tid = threadIdx.x;
  const float4 xx = *(const float4*)&X[(size_t)row * D_ + tid * 4];
  float v[4] = {xx.x, xx.y, xx.z, xx.w};
  float s = 0.f;
#pragma unroll
  for (int i = 0; i < 4; ++i) s += v[i] * v[i];
#pragma unroll
  for (int d = 1; d < 64; d <<= 1) s += __shfl_xor(s, d);
  __shared__ float red[4];
  if ((tid & 63) == 0) red[tid >> 6] = s;
  __syncthreads();
  s = red[0] + red[1] + red[2] + red[3];
  const float scale = rsqrtf(s * (1.0f / (float)D_) + 1e-5f);
  const float4 gg = *(const float4*)&G[tid * 4];
  us4 o;
  o[0] = f2bf(v[0] * scale * gg.x);
  o[1] = f2bf(v[1] * scale * gg.y);
  o[2] = f2bf(v[2] * scale * gg.z);
  o[3] = f2bf(v[3] * scale * gg.w);
  *(us4*)&Hout[(size_t)row * D_ + tid * 4] = o;
}

// ---------------- GEMM: C[M,N] = A[M,K](bf16) * W[N,K]^T(f32, cvt on the fly) ----------------
// 128x128 tile, BK=32. MODE 0: store; MODE 1: += RES(f32); MODE 2: gelu.
#define LSTR 40
template <int MODE, typename TO>
__global__ __launch_bounds__(256) void gemm_bt_k(const u16* __restrict__ A,
                                                 const float* __restrict__ W,
                                                 const float* __restrict__ RES,
                                                 TO* __restrict__ C, int N, int K) {
  __shared__ alignas(16) u16 As[128 * LSTR];
  __shared__ alignas(16) u16 Bs[128 * LSTR];
  const int tid = threadIdx.x;
  const int wv = tid >> 6, lane = tid & 63;
  const int r = lane & 15, quad = lane >> 4;
  const int bm = blockIdx.y * 128, bn = blockIdx.x * 128;
  const int row0 = (wv >> 1) * 64, col0 = (wv & 1) * 64;

  f32x4 acc[4][4] = {};

  const int c0row = tid >> 2, cgrp = tid & 3;  // rows 0..63
  const int c1row = 64 + c0row;                // rows 64..127

  for (int k0 = 0; k0 < K; k0 += 32) {
    short8 a0 = *(const short8*)&A[(size_t)(bm + c0row) * K + k0 + cgrp * 8];
    short8 a1 = *(const short8*)&A[(size_t)(bm + c1row) * K + k0 + cgrp * 8];
    short8 b0 = cvt8(&W[(size_t)(bn + c0row) * K + k0 + cgrp * 8]);
    short8 b1 = cvt8(&W[(size_t)(bn + c1row) * K + k0 + cgrp * 8]);
    *(short8*)&As[c0row * LSTR + cgrp * 8] = a0;
    *(short8*)&As[c1row * LSTR + cgrp * 8] = a1;
    *(short8*)&Bs[c0row * LSTR + cgrp * 8] = b0;
    *(short8*)&Bs[c1row * LSTR + cgrp * 8] = b1;
    __syncthreads();
    short8 af[4], bf[4];
#pragma unroll
    for (int mt = 0; mt < 4; ++mt)
      af[mt] = *(const short8*)&As[(row0 + mt * 16 + r) * LSTR + quad * 8];
#pragma unroll
    for (int nt = 0; nt < 4; ++nt)
      bf[nt] = *(const short8*)&Bs[(col0 + nt * 16 + r) * LSTR + quad * 8];
#pragma unroll
    for (int mt = 0; mt < 4; ++mt)
#pragma unroll
      for (int nt = 0; nt < 4; ++nt)
        acc[mt][nt] = __builtin_amdgcn_mfma_f32_16x16x32_bf16(af[mt], bf[nt], acc[mt][nt], 0, 0, 0);
    __syncthreads();
  }

#pragma unroll
  for (int mt = 0; mt < 4; ++mt) {
#pragma unroll
    for (int nt = 0; nt < 4; ++nt) {
#pragma unroll
      for (int i = 0; i < 4; ++i) {
        const int grow = bm + row0 + mt * 16 + quad * 4 + i;
        const int gcol = bn + col0 + nt * 16 + r;
        float v = acc[mt][nt][i];
        if (MODE == 1) v += RES[(size_t)grow * N + gcol];
        if (MODE == 2) v = 0.5f * v * (1.0f + erff(v * 0.70710678118f));
        if constexpr (sizeof(TO) == 2) C[(size_t)grow * N + gcol] = f2bf(v);
        else                           C[(size_t)grow * N + gcol] = v;
      }
    }
  }
}

// ---------------- Flash attention v2: ONE WAVE per block, 16 q-rows, no barriers ----------------
// K fragments loaded direct global->reg; V transposed into padded LDS; causal-exact trip count.
#define SCL 0.18033688011112042f  /* 0.125 * log2(e) */
__global__ __launch_bounds__(64, 4) void attn_k(const u16* __restrict__ Q,
                                                const u16* __restrict__ Kx,
                                                const u16* __restrict__ Vx,
                                                u16* __restrict__ O) {
  __shared__ alignas(16) u16 Vs[64 * 40];  // V^T [dh 0..63][key 0..31 + pad]
  __shared__ alignas(16) u16 Ps[16 * 40];  // P   [qrow 0..15][key 0..31 + pad]

  const int lane = threadIdx.x;
  const int r = lane & 15, quad = lane >> 4;
  const int bh = blockIdx.y;
  const int b = bh >> 4, hh = bh & 15;
  const int qbase = blockIdx.x * 16;
  const size_t base = (size_t)b * S_ * D_ + (size_t)hh * DH_;
  const u16* Qb = Q + base;
  const u16* Kb = Kx + base;
  const u16* Vb = Vx + base;

  // Q A-fragments (m = r -> row qbase+r), two 32-wide dh halves
  const short8 qf0 = *(const short8*)&Qb[(size_t)(qbase + r) * D_ + quad * 8];
  const short8 qf1 = *(const short8*)&Qb[(size_t)(qbase + r) * D_ + 32 + quad * 8];

  f32x4 oacc[4] = {};
  float m_i[4], l_i[4];
  int qrow[4];
#pragma unroll
  for (int i = 0; i < 4; ++i) { m_i[i] = -3.0e38f; l_i[i] = 0.f; qrow[i] = qbase + quad * 4 + i; }

  const int niter = (qbase + 16 + 31) >> 5;
  const int vkey = lane & 31, vg0 = lane >> 5;  // V staging: key + dh-group base

  short8 kf0[2], kf1[2], vv[4];
  {
    const int j0 = 0;
    kf0[0] = *(const short8*)&Kb[(size_t)(j0 + r) * D_ + quad * 8];
    kf0[1] = *(const short8*)&Kb[(size_t)(j0 + r) * D_ + 32 + quad * 8];
    kf1[0] = *(const short8*)&Kb[(size_t)(j0 + 16 + r) * D_ + quad * 8];
    kf1[1] = *(const short8*)&Kb[(size_t)(j0 + 16 + r) * D_ + 32 + quad * 8];
#pragma unroll
    for (int jj = 0; jj < 4; ++jj)
      vv[jj] = *(const short8*)&Vb[(size_t)(j0 + vkey) * D_ + (vg0 + 2 * jj) * 8];
  }

  for (int it = 0; it < niter; ++it) {
    const int j0 = it * 32;
    // V^T transpose into LDS (wave-local, no barrier)
#pragma unroll
    for (int jj = 0; jj < 4; ++jj) {
      const int dh0 = (vg0 + 2 * jj) * 8;
#pragma unroll
      for (int e = 0; e < 8; ++e) Vs[(dh0 + e) * 40 + vkey] = (u16)vv[jj][e];
    }
    // prefetch next tile
    short8 nkf0[2], nkf1[2], nvv[4];
    if (it + 1 < niter) {
      const int j1 = j0 + 32;
      nkf0[0] = *(const short8*)&Kb[(size_t)(j1 + r) * D_ + quad * 8];
      nkf0[1] = *(const short8*)&Kb[(size_t)(j1 + r) * D_ + 32 + quad * 8];
      nkf1[0] = *(const short8*)&Kb[(size_t)(j1 + 16 + r) * D_ + quad * 8];
      nkf1[1] = *(const short8*)&Kb[(size_t)(j1 + 16 + r) * D_ + 32 + quad * 8];
#pragma unroll
      for (int jj = 0; jj < 4; ++jj)
        nvv[jj] = *(const short8*)&Vb[(size_t)(j1 + vkey) * D_ + (vg0 + 2 * jj) * 8];
    }

    // S = Q K^T (two 16-key column tiles, K frags from registers)
    f32x4 z0 = {}, z1 = {};
    z0 = __builtin_amdgcn_mfma_f32_16x16x32_bf16(qf0, kf0[0], z0, 0, 0, 0);
    z0 = __builtin_amdgcn_mfma_f32_16x16x32_bf16(qf1, kf0[1], z0, 0, 0, 0);
    z1 = __builtin_amdgcn_mfma_f32_16x16x32_bf16(qf0, kf1[0], z1, 0, 0, 0);
    z1 = __builtin_amdgcn_mfma_f32_16x16x32_bf16(qf1, kf1[1], z1, 0, 0, 0);

    const bool masked = (j0 + 31 > qbase);  // only diagonal tiles need masking
    // online softmax in base-2 units; sentinel keeps everything finite
#pragma unroll
    for (int i = 0; i < 4; ++i) {
      float v0 = z0[i] * SCL;
      float v1 = z1[i] * SCL;
      if (masked) {
        if (j0 + r > qrow[i]) v0 = -3.0e38f;
        if (j0 + 16 + r > qrow[i]) v1 = -3.0e38f;
      }
      float mt = fmaxf(v0, v1);
#pragma unroll
      for (int d = 1; d < 16; d <<= 1) mt = fmaxf(mt, __shfl_xor(mt, d));
      const float mnew = fmaxf(m_i[i], mt);
      const float alpha = exp2f(m_i[i] - mnew);
      const float p0 = exp2f(v0 - mnew);
      const float p1 = exp2f(v1 - mnew);
      float ps = p0 + p1;
#pragma unroll
      for (int d = 1; d < 16; d <<= 1) ps += __shfl_xor(ps, d);
      l_i[i] = l_i[i] * alpha + ps;
      m_i[i] = mnew;
#pragma unroll
      for (int nt = 0; nt < 4; ++nt) oacc[nt][i] *= alpha;
      Ps[(quad * 4 + i) * 40 + r] = f2bf(p0);
      Ps[(quad * 4 + i) * 40 + 16 + r] = f2bf(p1);
    }

    asm volatile("s_waitcnt lgkmcnt(0)" ::: "memory");
    const short8 pf = *(const short8*)&Ps[r * 40 + quad * 8];
#pragma unroll
    for (int nt = 0; nt < 4; ++nt) {
      const short8 vf = *(const short8*)&Vs[(nt * 16 + r) * 40 + quad * 8];
      oacc[nt] = __builtin_amdgcn_mfma_f32_16x16x32_bf16(pf, vf, oacc[nt], 0, 0, 0);
    }

    kf0[0] = nkf0[0]; kf0[1] = nkf0[1];
    kf1[0] = nkf1[0]; kf1[1] = nkf1[1];
#pragma unroll
    for (int jj = 0; jj < 4; ++jj) vv[jj] = nvv[jj];
  }

#pragma unroll
  for (int nt = 0; nt < 4; ++nt)
#pragma unroll
    for (int i = 0; i < 4; ++i) {
      const float inv_l = 1.0f / l_i[i];
      O[base + (size_t)qrow[i] * D_ + nt * 16 + r] = f2bf(oacc[nt][i] * inv_l);
    }
}

extern "C" void kernel_launch(void* const* d_in, const int* in_sizes, int n_in,
                              void* d_out, int out_size, void* d_ws, size_t ws_size,
                              hipStream_t stream) {
  (void)in_sizes; (void)n_in; (void)out_size; (void)ws_size;
  const float* x   = (const float*)d_in[0];
  const float* wq  = (const float*)d_in[1];
  const float* wk  = (const float*)d_in[2];
  const float* wvp = (const float*)d_in[3];
  const float* wo  = (const float*)d_in[4];
  const float* w1  = (const float*)d_in[5];
  const float* w2  = (const float*)d_in[6];
  const float* g1  = (const float*)d_in[7];
  const float* g2  = (const float*)d_in[8];
  float* out = (float*)d_out;  // also hosts x2 (f32 residual stream 2)

  u16* ws = (u16*)d_ws;
  const size_t TD = (size_t)M_TOK * D_;  // 4M elems
  u16* h  = ws;            // slot0: h, later o, later t[0]
  u16* q  = ws + 1 * TD;   // slot1
  u16* k  = ws + 2 * TD;   // slot2
  u16* v  = ws + 3 * TD;   // slot3
  u16* h2 = ws + 4 * TD;   // slot4
  u16* o  = h;
  u16* t  = ws;            // spans slots 0..3

  const dim3 blk(256);
  const dim3 gD(D_ / 128, M_TOK / 128);   // (8, 32)
  const dim3 gF(FF_ / 128, M_TOK / 128);  // (32, 32)

  rmsnorm_k<<<M_TOK, blk, 0, stream>>>(x, g1, h);
  gemm_bt_k<0, u16><<<gD, blk, 0, stream>>>(h, wq, nullptr, q, D_, D_);
  gemm_bt_k<0, u16><<<gD, blk, 0, stream>>>(h, wk, nullptr, k, D_, D_);
  gemm_bt_k<0, u16><<<gD, blk, 0, stream>>>(h, wvp, nullptr, v, D_, D_);
  attn_k<<<dim3(S_ / 16, B_ * H_), dim3(64), 0, stream>>>(q, k, v, o);
  gemm_bt_k<1, float><<<gD, blk, 0, stream>>>(o, wo, x, out, D_, D_);     // x2 -> d_out (f32)
  rmsnorm_k<<<M_TOK, blk, 0, stream>>>(out, g2, h2);
  gemm_bt_k<2, u16><<<gF, blk, 0, stream>>>(h2, w1, nullptr, t, FF_, D_);
  gemm_bt_k<1, float><<<gD, blk, 0, stream>>>(t, w2, out, out, D_, FF_);  // out = t@w2^T + x2
}

// Round 9
// 730.091 us; speedup vs baseline: 1.0170x; 1.0170x over previous
//
#include <hip/hip_runtime.h>
#include <cstdint>

#define B_ 2
#define S_ 2048
#define D_ 1024
#define H_ 16
#define DH_ 64
#define FF_ 4096
#define M_TOK (B_ * S_)  // 4096 token rows

typedef __attribute__((ext_vector_type(8))) short short8;
typedef __attribute__((ext_vector_type(4))) float f32x4;
typedef __attribute__((ext_vector_type(4))) unsigned short us4;

typedef unsigned short u16;

__device__ __forceinline__ float bf2f(u16 u) {
  union { uint32_t u; float f; } x;
  x.u = ((uint32_t)u) << 16;
  return x.f;
}
__device__ __forceinline__ u16 f2bf(float f) {
  union { float f; uint32_t u; } x;
  x.f = f;
  uint32_t r = x.u + 0x7FFFu + ((x.u >> 16) & 1u);  // RNE
  return (u16)(r >> 16);
}
// convert 8 contiguous f32 -> short8 (bf16 bits)
__device__ __forceinline__ short8 cvt8(const float* p) {
  const float4 a = *(const float4*)p;
  const float4 b = *(const float4*)(p + 4);
  short8 r;
  r[0] = (short)f2bf(a.x); r[1] = (short)f2bf(a.y);
  r[2] = (short)f2bf(a.z); r[3] = (short)f2bf(a.w);
  r[4] = (short)f2bf(b.x); r[5] = (short)f2bf(b.y);
  r[6] = (short)f2bf(b.z); r[7] = (short)f2bf(b.w);
  return r;
}

// ---------------- RMSNorm: one block per token row (f32 in, bf16 out) ----------------
__global__ __launch_bounds__(256) void rmsnorm_k(const float* __restrict__ X,
                                                 const float* __restrict__ G,
                                                 u16* __restrict__ Hout) {
  const int row = blockIdx.x;
  const int tid = threadIdx.x;
  const float4 xx = *(const float4*)&X[(size_t)row * D_ + tid * 4];
  float v[4] = {xx.x, xx.y, xx.z, xx.w};
  float s = 0.f;
#pragma unroll
  for (int i = 0; i < 4; ++i) s += v[i] * v[i];
#pragma unroll
  for (int d = 1; d < 64; d <<= 1) s += __shfl_xor(s, d);
  __shared__ float red[4];
  if ((tid & 63) == 0) red[tid >> 6] = s;
  __syncthreads();
  s = red[0] + red[1] + red[2] + red[3];
  const float scale = rsqrtf(s * (1.0f / (float)D_) + 1e-5f);
  const float4 gg = *(const float4*)&G[tid * 4];
  us4 o;
  o[0] = f2bf(v[0] * scale * gg.x);
  o[1] = f2bf(v[1] * scale * gg.y);
  o[2] = f2bf(v[2] * scale * gg.z);
  o[3] = f2bf(v[3] * scale * gg.w);
  *(us4*)&Hout[(size_t)row * D_ + tid * 4] = o;
}

// ---------------- GEMM: C[M,N] = A[M,K](bf16) * W[N,K]^T(f32, cvt on the fly) ----------------
// 128x128 tile, BK=32. MODE 0: store; MODE 1: += RES(f32); MODE 2: gelu;
// MODE 3: store transposed V^T layout [bh][dh][s] (for attention PV fragments).
#define LSTR 40
template <int MODE, typename TO>
__global__ __launch_bounds__(256) void gemm_bt_k(const u16* __restrict__ A,
                                                 const float* __restrict__ W,
                                                 const float* __restrict__ RES,
                                                 TO* __restrict__ C, int N, int K) {
  __shared__ alignas(16) u16 As[128 * LSTR];
  __shared__ alignas(16) u16 Bs[128 * LSTR];
  const int tid = threadIdx.x;
  const int wv = tid >> 6, lane = tid & 63;
  const int r = lane & 15, quad = lane >> 4;
  const int bm = blockIdx.y * 128, bn = blockIdx.x * 128;
  const int row0 = (wv >> 1) * 64, col0 = (wv & 1) * 64;

  f32x4 acc[4][4] = {};

  const int c0row = tid >> 2, cgrp = tid & 3;  // rows 0..63
  const int c1row = 64 + c0row;                // rows 64..127

  for (int k0 = 0; k0 < K; k0 += 32) {
    short8 a0 = *(const short8*)&A[(size_t)(bm + c0row) * K + k0 + cgrp * 8];
    short8 a1 = *(const short8*)&A[(size_t)(bm + c1row) * K + k0 + cgrp * 8];
    short8 b0 = cvt8(&W[(size_t)(bn + c0row) * K + k0 + cgrp * 8]);
    short8 b1 = cvt8(&W[(size_t)(bn + c1row) * K + k0 + cgrp * 8]);
    *(short8*)&As[c0row * LSTR + cgrp * 8] = a0;
    *(short8*)&As[c1row * LSTR + cgrp * 8] = a1;
    *(short8*)&Bs[c0row * LSTR + cgrp * 8] = b0;
    *(short8*)&Bs[c1row * LSTR + cgrp * 8] = b1;
    __syncthreads();
    short8 af[4], bf[4];
#pragma unroll
    for (int mt = 0; mt < 4; ++mt)
      af[mt] = *(const short8*)&As[(row0 + mt * 16 + r) * LSTR + quad * 8];
#pragma unroll
    for (int nt = 0; nt < 4; ++nt)
      bf[nt] = *(const short8*)&Bs[(col0 + nt * 16 + r) * LSTR + quad * 8];
#pragma unroll
    for (int mt = 0; mt < 4; ++mt)
#pragma unroll
      for (int nt = 0; nt < 4; ++nt)
        acc[mt][nt] = __builtin_amdgcn_mfma_f32_16x16x32_bf16(af[mt], bf[nt], acc[mt][nt], 0, 0, 0);
    __syncthreads();
  }

  if constexpr (MODE == 3) {
    // V^T store: token grow -> (b = grow>>11, s = grow&2047); col -> (h = gcol>>6, dh = gcol&63)
    // vt[((b*16+h)*64+dh)*2048 + s], 4 consecutive s per (mt,nt) -> one us4 store
#pragma unroll
    for (int mt = 0; mt < 4; ++mt) {
      const int grow0 = bm + row0 + mt * 16 + quad * 4;
#pragma unroll
      for (int nt = 0; nt < 4; ++nt) {
        const int gcol = bn + col0 + nt * 16 + r;
        us4 o;
#pragma unroll
        for (int i = 0; i < 4; ++i) o[i] = f2bf(acc[mt][nt][i]);
        const size_t addr = ((size_t)((grow0 >> 11) * 16 + (gcol >> 6)) * 64 + (gcol & 63)) * 2048 + (grow0 & 2047);
        *(us4*)&C[addr] = o;
      }
    }
  } else {
#pragma unroll
    for (int mt = 0; mt < 4; ++mt) {
#pragma unroll
      for (int nt = 0; nt < 4; ++nt) {
#pragma unroll
        for (int i = 0; i < 4; ++i) {
          const int grow = bm + row0 + mt * 16 + quad * 4 + i;
          const int gcol = bn + col0 + nt * 16 + r;
          float v = acc[mt][nt][i];
          if (MODE == 1) v += RES[(size_t)grow * N + gcol];
          if (MODE == 2) v = 0.5f * v * (1.0f + erff(v * 0.70710678118f));
          if constexpr (sizeof(TO) == 2) C[(size_t)grow * N + gcol] = f2bf(v);
          else                           C[(size_t)grow * N + gcol] = v;
        }
      }
    }
  }
}

// ---------------- Flash attention v3: fixed-max softmax, l via ones-MFMA, zero shuffles ----------------
// Block = 256 thr = 4 independent waves; wave owns 16 q-rows. K and V^T fragments direct global->reg.
#define SCL 0.18033688011112042f  /* 0.125 * log2(e) */
__global__ __launch_bounds__(256, 4) void attn_k(const u16* __restrict__ Q,
                                                 const u16* __restrict__ Kx,
                                                 const u16* __restrict__ VT,
                                                 u16* __restrict__ O) {
  __shared__ alignas(16) u16 Ps[4][16 * 40];  // per-wave P tile (bf16, A-layout source)

  const int tid = threadIdx.x;
  const int wv = tid >> 6, lane = tid & 63;
  const int r = lane & 15, quad = lane >> 4;
  const int bh = blockIdx.y;
  const int b = bh >> 4, hh = bh & 15;
  const int qbase = blockIdx.x * 64 + wv * 16;
  const size_t base = (size_t)b * S_ * D_ + (size_t)hh * DH_;
  const u16* Qb = Q + base;
  const u16* Kb = Kx + base;
  const u16* VTb = VT + (size_t)bh * 64 * 2048;  // [dh][s]
  u16* Psw = &Ps[wv][0];

  const short8 qf0 = *(const short8*)&Qb[(size_t)(qbase + r) * D_ + quad * 8];
  const short8 qf1 = *(const short8*)&Qb[(size_t)(qbase + r) * D_ + 32 + quad * 8];

  short8 onesv;
#pragma unroll
  for (int e = 0; e < 8; ++e) onesv[e] = (short)0x3F80;  // bf16 1.0

  f32x4 oacc[4] = {};
  f32x4 lacc = {};
  int qrow[4];
#pragma unroll
  for (int i = 0; i < 4; ++i) qrow[i] = qbase + quad * 4 + i;

  const int niter = (qbase + 16 + 31) >> 5;

  short8 kf0[2], kf1[2], vf[4];
  kf0[0] = *(const short8*)&Kb[(size_t)r * D_ + quad * 8];
  kf0[1] = *(const short8*)&Kb[(size_t)r * D_ + 32 + quad * 8];
  kf1[0] = *(const short8*)&Kb[(size_t)(16 + r) * D_ + quad * 8];
  kf1[1] = *(const short8*)&Kb[(size_t)(16 + r) * D_ + 32 + quad * 8];
#pragma unroll
  for (int nt = 0; nt < 4; ++nt)
    vf[nt] = *(const short8*)&VTb[(size_t)(nt * 16 + r) * 2048 + quad * 8];

  for (int it = 0; it < niter; ++it) {
    const int j0 = it * 32;

    // S = Q K^T (two 16-key tiles)
    f32x4 z0 = {}, z1 = {};
    z0 = __builtin_amdgcn_mfma_f32_16x16x32_bf16(qf0, kf0[0], z0, 0, 0, 0);
    z0 = __builtin_amdgcn_mfma_f32_16x16x32_bf16(qf1, kf0[1], z0, 0, 0, 0);
    z1 = __builtin_amdgcn_mfma_f32_16x16x32_bf16(qf0, kf1[0], z1, 0, 0, 0);
    z1 = __builtin_amdgcn_mfma_f32_16x16x32_bf16(qf1, kf1[1], z1, 0, 0, 0);

    // prefetch next K tile (kf consumed above; overwrite in place)
    short8 nvf[4];
    const bool more = (it + 1 < niter);
    if (more) {
      const int j1 = j0 + 32;
      kf0[0] = *(const short8*)&Kb[(size_t)(j1 + r) * D_ + quad * 8];
      kf0[1] = *(const short8*)&Kb[(size_t)(j1 + r) * D_ + 32 + quad * 8];
      kf1[0] = *(const short8*)&Kb[(size_t)(j1 + 16 + r) * D_ + quad * 8];
      kf1[1] = *(const short8*)&Kb[(size_t)(j1 + 16 + r) * D_ + 32 + quad * 8];
#pragma unroll
      for (int nt = 0; nt < 4; ++nt)
        nvf[nt] = *(const short8*)&VTb[(size_t)(nt * 16 + r) * 2048 + j1 + quad * 8];
    }

    // fixed-max softmax: p = exp2(s * 0.125 * log2e); masked -> exp2(-128) = 0
    const bool masked = (j0 + 31 > qbase);
#pragma unroll
    for (int i = 0; i < 4; ++i) {
      float v0 = z0[i] * SCL;
      float v1 = z1[i] * SCL;
      if (masked) {
        if (j0 + r > qrow[i]) v0 = -128.f;
        if (j0 + 16 + r > qrow[i]) v1 = -128.f;
      }
      Psw[(quad * 4 + i) * 40 + r] = f2bf(exp2f(v0));
      Psw[(quad * 4 + i) * 40 + 16 + r] = f2bf(exp2f(v1));
    }

    asm volatile("s_waitcnt lgkmcnt(0)" ::: "memory");
    const short8 pf = *(const short8*)&Psw[r * 40 + quad * 8];
#pragma unroll
    for (int nt = 0; nt < 4; ++nt)
      oacc[nt] = __builtin_amdgcn_mfma_f32_16x16x32_bf16(pf, vf[nt], oacc[nt], 0, 0, 0);
    lacc = __builtin_amdgcn_mfma_f32_16x16x32_bf16(pf, onesv, lacc, 0, 0, 0);

    if (more) {
#pragma unroll
      for (int nt = 0; nt < 4; ++nt) vf[nt] = nvf[nt];
    }
  }

#pragma unroll
  for (int i = 0; i < 4; ++i) {
    const float inv_l = 1.0f / lacc[i];
#pragma unroll
    for (int nt = 0; nt < 4; ++nt)
      O[base + (size_t)qrow[i] * D_ + nt * 16 + r] = f2bf(oacc[nt][i] * inv_l);
  }
}

extern "C" void kernel_launch(void* const* d_in, const int* in_sizes, int n_in,
                              void* d_out, int out_size, void* d_ws, size_t ws_size,
                              hipStream_t stream) {
  (void)in_sizes; (void)n_in; (void)out_size; (void)ws_size;
  const float* x   = (const float*)d_in[0];
  const float* wq  = (const float*)d_in[1];
  const float* wk  = (const float*)d_in[2];
  const float* wvp = (const float*)d_in[3];
  const float* wo  = (const float*)d_in[4];
  const float* w1  = (const float*)d_in[5];
  const float* w2  = (const float*)d_in[6];
  const float* g1  = (const float*)d_in[7];
  const float* g2  = (const float*)d_in[8];
  float* out = (float*)d_out;  // also hosts x2 (f32 residual stream 2)

  u16* ws = (u16*)d_ws;
  const size_t TD = (size_t)M_TOK * D_;  // 4M elems
  u16* h  = ws;            // slot0: h, later o, later t[0]
  u16* q  = ws + 1 * TD;   // slot1
  u16* k  = ws + 2 * TD;   // slot2
  u16* vt = ws + 3 * TD;   // slot3: V^T [bh][dh][s]
  u16* h2 = ws + 4 * TD;   // slot4
  u16* o  = h;
  u16* t  = ws;            // FFN1 out spans slots 0..3

  const dim3 blk(256);
  const dim3 gD(D_ / 128, M_TOK / 128);   // (8, 32)
  const dim3 gF(FF_ / 128, M_TOK / 128);  // (32, 32)

  rmsnorm_k<<<M_TOK, blk, 0, stream>>>(x, g1, h);
  gemm_bt_k<0, u16><<<gD, blk, 0, stream>>>(h, wq, nullptr, q, D_, D_);
  gemm_bt_k<0, u16><<<gD, blk, 0, stream>>>(h, wk, nullptr, k, D_, D_);
  gemm_bt_k<3, u16><<<gD, blk, 0, stream>>>(h, wvp, nullptr, vt, D_, D_);  // V^T store
  attn_k<<<dim3(S_ / 64, B_ * H_), blk, 0, stream>>>(q, k, vt, o);
  gemm_bt_k<1, float><<<gD, blk, 0, stream>>>(o, wo, x, out, D_, D_);      // x2 -> d_out (f32)
  rmsnorm_k<<<M_TOK, blk, 0, stream>>>(out, g2, h2);
  gemm_bt_k<2, u16><<<gF, blk, 0, stream>>>(h2, w1, nullptr, t, FF_, D_);
  gemm_bt_k<1, float><<<gD, blk, 0, stream>>>(t, w2, out, out, D_, FF_);   // out = t@w2^T + x2
}

// Round 10
// 616.074 us; speedup vs baseline: 1.2053x; 1.1851x over previous
//
#include <hip/hip_runtime.h>
#include <cstdint>

#define B_ 2
#define S_ 2048
#define D_ 1024
#define H_ 16
#define DH_ 64
#define FF_ 4096
#define M_TOK (B_ * S_)  // 4096 token rows

typedef __attribute__((ext_vector_type(8))) short short8;
typedef __attribute__((ext_vector_type(4))) float f32x4;
typedef __attribute__((ext_vector_type(4))) unsigned short us4;

typedef unsigned short u16;

__device__ __forceinline__ float bf2f(u16 u) {
  union { uint32_t u; float f; } x;
  x.u = ((uint32_t)u) << 16;
  return x.f;
}
__device__ __forceinline__ u16 f2bf(float f) {
  union { float f; uint32_t u; } x;
  x.f = f;
  uint32_t r = x.u + 0x7FFFu + ((x.u >> 16) & 1u);  // RNE
  return (u16)(r >> 16);
}
// convert 8 contiguous f32 -> short8 (bf16 bits)
__device__ __forceinline__ short8 cvt8(const float* p) {
  const float4 a = *(const float4*)p;
  const float4 b = *(const float4*)(p + 4);
  short8 r;
  r[0] = (short)f2bf(a.x); r[1] = (short)f2bf(a.y);
  r[2] = (short)f2bf(a.z); r[3] = (short)f2bf(a.w);
  r[4] = (short)f2bf(b.x); r[5] = (short)f2bf(b.y);
  r[6] = (short)f2bf(b.z); r[7] = (short)f2bf(b.w);
  return r;
}

// ---------------- RMSNorm: one block per token row (f32 in, bf16 out) ----------------
__global__ __launch_bounds__(256) void rmsnorm_k(const float* __restrict__ X,
                                                 const float* __restrict__ G,
                                                 u16* __restrict__ Hout) {
  const int row = blockIdx.x;
  const int tid = threadIdx.x;
  const float4 xx = *(const float4*)&X[(size_t)row * D_ + tid * 4];
  float v[4] = {xx.x, xx.y, xx.z, xx.w};
  float s = 0.f;
#pragma unroll
  for (int i = 0; i < 4; ++i) s += v[i] * v[i];
#pragma unroll
  for (int d = 1; d < 64; d <<= 1) s += __shfl_xor(s, d);
  __shared__ float red[4];
  if ((tid & 63) == 0) red[tid >> 6] = s;
  __syncthreads();
  s = red[0] + red[1] + red[2] + red[3];
  const float scale = rsqrtf(s * (1.0f / (float)D_) + 1e-5f);
  const float4 gg = *(const float4*)&G[tid * 4];
  us4 o;
  o[0] = f2bf(v[0] * scale * gg.x);
  o[1] = f2bf(v[1] * scale * gg.y);
  o[2] = f2bf(v[2] * scale * gg.z);
  o[3] = f2bf(v[3] * scale * gg.w);
  *(us4*)&Hout[(size_t)row * D_ + tid * 4] = o;
}

// ---------------- GEMM: C[M,N] = A[M,K](bf16) * W[N,K]^T(f32, cvt on the fly) ----------------
// 128x128 tile, BK=32. MODE 0: store; MODE 1: += RES(f32); MODE 2: gelu;
// MODE 3: store transposed V^T layout [bh][dh][s] (for attention PV fragments).
#define LSTR 40
template <int MODE, typename TO>
__global__ __launch_bounds__(256) void gemm_bt_k(const u16* __restrict__ A,
                                                 const float* __restrict__ W,
                                                 const float* __restrict__ RES,
                                                 TO* __restrict__ C, int N, int K) {
  __shared__ alignas(16) u16 As[128 * LSTR];
  __shared__ alignas(16) u16 Bs[128 * LSTR];
  const int tid = threadIdx.x;
  const int wv = tid >> 6, lane = tid & 63;
  const int r = lane & 15, quad = lane >> 4;
  const int bm = blockIdx.y * 128, bn = blockIdx.x * 128;
  const int row0 = (wv >> 1) * 64, col0 = (wv & 1) * 64;

  f32x4 acc[4][4] = {};

  const int c0row = tid >> 2, cgrp = tid & 3;  // rows 0..63
  const int c1row = 64 + c0row;                // rows 64..127

  for (int k0 = 0; k0 < K; k0 += 32) {
    short8 a0 = *(const short8*)&A[(size_t)(bm + c0row) * K + k0 + cgrp * 8];
    short8 a1 = *(const short8*)&A[(size_t)(bm + c1row) * K + k0 + cgrp * 8];
    short8 b0 = cvt8(&W[(size_t)(bn + c0row) * K + k0 + cgrp * 8]);
    short8 b1 = cvt8(&W[(size_t)(bn + c1row) * K + k0 + cgrp * 8]);
    *(short8*)&As[c0row * LSTR + cgrp * 8] = a0;
    *(short8*)&As[c1row * LSTR + cgrp * 8] = a1;
    *(short8*)&Bs[c0row * LSTR + cgrp * 8] = b0;
    *(short8*)&Bs[c1row * LSTR + cgrp * 8] = b1;
    __syncthreads();
    short8 af[4], bf[4];
#pragma unroll
    for (int mt = 0; mt < 4; ++mt)
      af[mt] = *(const short8*)&As[(row0 + mt * 16 + r) * LSTR + quad * 8];
#pragma unroll
    for (int nt = 0; nt < 4; ++nt)
      bf[nt] = *(const short8*)&Bs[(col0 + nt * 16 + r) * LSTR + quad * 8];
#pragma unroll
    for (int mt = 0; mt < 4; ++mt)
#pragma unroll
      for (int nt = 0; nt < 4; ++nt)
        acc[mt][nt] = __builtin_amdgcn_mfma_f32_16x16x32_bf16(af[mt], bf[nt], acc[mt][nt], 0, 0, 0);
    __syncthreads();
  }

  if constexpr (MODE == 3) {
    // V^T store: token grow -> (b = grow>>11, s = grow&2047); col -> (h = gcol>>6, dh = gcol&63)
#pragma unroll
    for (int mt = 0; mt < 4; ++mt) {
      const int grow0 = bm + row0 + mt * 16 + quad * 4;
#pragma unroll
      for (int nt = 0; nt < 4; ++nt) {
        const int gcol = bn + col0 + nt * 16 + r;
        us4 o;
#pragma unroll
        for (int i = 0; i < 4; ++i) o[i] = f2bf(acc[mt][nt][i]);
        const size_t addr = ((size_t)((grow0 >> 11) * 16 + (gcol >> 6)) * 64 + (gcol & 63)) * 2048 + (grow0 & 2047);
        *(us4*)&C[addr] = o;
      }
    }
  } else {
#pragma unroll
    for (int mt = 0; mt < 4; ++mt) {
#pragma unroll
      for (int nt = 0; nt < 4; ++nt) {
#pragma unroll
        for (int i = 0; i < 4; ++i) {
          const int grow = bm + row0 + mt * 16 + quad * 4 + i;
          const int gcol = bn + col0 + nt * 16 + r;
          float v = acc[mt][nt][i];
          if (MODE == 1) v += RES[(size_t)grow * N + gcol];
          if (MODE == 2) v = 0.5f * v * (1.0f + erff(v * 0.70710678118f));
          if constexpr (sizeof(TO) == 2) C[(size_t)grow * N + gcol] = f2bf(v);
          else                           C[(size_t)grow * N + gcol] = v;
        }
      }
    }
  }
}

// ---------------- Flash attention v4: 128 q-rows/block, KV tile shared via LDS ----------------
// 4 waves x 32 q-rows; 32-key KV tiles double-buffered in LDS; fixed-max exp2 softmax;
// l via ones-MFMA; heavy blocks dispatched first (bx = 15 - blockIdx.x) for LPT balance.
#define SCL 0.18033688011112042f  /* 0.125 * log2(e) */
__global__ __launch_bounds__(256, 2) void attn_k(const u16* __restrict__ Q,
                                                 const u16* __restrict__ Kx,
                                                 const u16* __restrict__ VT,
                                                 u16* __restrict__ O) {
  __shared__ alignas(16) u16 Ks[2][32 * 72];  // [key][dh 0..63 + pad]
  __shared__ alignas(16) u16 Vs[2][64 * 40];  // [dh][key 0..31 + pad]
  __shared__ alignas(16) u16 Ps[4][32 * 40];  // per-wave P [qrow 0..31][key + pad]

  const int tid = threadIdx.x;
  const int wv = tid >> 6, lane = tid & 63;
  const int r = lane & 15, quad = lane >> 4;
  const int bh = blockIdx.y;
  const int b = bh >> 4, hh = bh & 15;
  const int bx = 15 - (int)blockIdx.x;  // heavy blocks first
  const int qbase = bx * 128;
  const int m0 = qbase + wv * 32;       // this wave's 32 rows
  const size_t base = (size_t)b * S_ * D_ + (size_t)hh * DH_;
  const u16* Qb = Q + base;
  const u16* Kb = Kx + base;
  const u16* VTb = VT + (size_t)bh * 64 * 2048;  // [dh][s]
  u16* Psw = &Ps[wv][0];

  // Q A-fragments: 2 row-frags x 2 dh-halves
  short8 qf[2][2];
#pragma unroll
  for (int f = 0; f < 2; ++f) {
    qf[f][0] = *(const short8*)&Qb[(size_t)(m0 + f * 16 + r) * D_ + quad * 8];
    qf[f][1] = *(const short8*)&Qb[(size_t)(m0 + f * 16 + r) * D_ + 32 + quad * 8];
  }

  short8 onesv;
#pragma unroll
  for (int e = 0; e < 8; ++e) onesv[e] = (short)0x3F80;  // bf16 1.0

  f32x4 oacc[2][4] = {};
  f32x4 lacc[2] = {};

  const int niter = 4 * bx + 4;  // keys 0 .. qbase+127

  // staging lanes
  const int krow = tid >> 3, kg = tid & 7;  // K: 32 rows x 8 chunks(16B)
  const int vrow = tid >> 2, vg = tid & 3;  // VT: 64 rows x 4 chunks(16B)

  // stage tile 0 into buf 0
  *(short8*)&Ks[0][krow * 72 + kg * 8] = *(const short8*)&Kb[(size_t)krow * D_ + kg * 8];
  *(short8*)&Vs[0][vrow * 40 + vg * 8] = *(const short8*)&VTb[(size_t)vrow * 2048 + vg * 8];

  int cur = 0;
  for (int it = 0; it < niter; ++it) {
    const int j0 = it * 32;
    __syncthreads();  // staging of buf `cur` complete; prior compute on cur^1 complete

    if (it + 1 < niter) {
      const int j1 = j0 + 32;
      *(short8*)&Ks[cur ^ 1][krow * 72 + kg * 8] =
          *(const short8*)&Kb[(size_t)(j1 + krow) * D_ + kg * 8];
      *(short8*)&Vs[cur ^ 1][vrow * 40 + vg * 8] =
          *(const short8*)&VTb[(size_t)vrow * 2048 + j1 + vg * 8];
    }

    // S = Q K^T: 2 row-frags x 2 key-tiles
    f32x4 z[2][2];
#pragma unroll
    for (int kt = 0; kt < 2; ++kt) {
      const short8 kf0 = *(const short8*)&Ks[cur][(kt * 16 + r) * 72 + quad * 8];
      const short8 kf1 = *(const short8*)&Ks[cur][(kt * 16 + r) * 72 + 32 + quad * 8];
#pragma unroll
      for (int f = 0; f < 2; ++f) {
        f32x4 zz = {};
        zz = __builtin_amdgcn_mfma_f32_16x16x32_bf16(qf[f][0], kf0, zz, 0, 0, 0);
        zz = __builtin_amdgcn_mfma_f32_16x16x32_bf16(qf[f][1], kf1, zz, 0, 0, 0);
        z[f][kt] = zz;
      }
    }

    // fixed-max softmax -> P (bf16) in per-wave LDS
    const bool masked = (j0 + 31 > m0);
#pragma unroll
    for (int f = 0; f < 2; ++f)
#pragma unroll
      for (int i = 0; i < 4; ++i) {
        const int qrow = m0 + f * 16 + quad * 4 + i;
        float v0 = z[f][0][i] * SCL;
        float v1 = z[f][1][i] * SCL;
        if (masked) {
          if (j0 + r > qrow) v0 = -128.f;
          if (j0 + 16 + r > qrow) v1 = -128.f;
        }
        Psw[(f * 16 + quad * 4 + i) * 40 + r] = f2bf(exp2f(v0));
        Psw[(f * 16 + quad * 4 + i) * 40 + 16 + r] = f2bf(exp2f(v1));
      }

    asm volatile("s_waitcnt lgkmcnt(0)" ::: "memory");

    short8 vf[4];
#pragma unroll
    for (int nt = 0; nt < 4; ++nt)
      vf[nt] = *(const short8*)&Vs[cur][(nt * 16 + r) * 40 + quad * 8];
#pragma unroll
    for (int f = 0; f < 2; ++f) {
      const short8 pf = *(const short8*)&Psw[(f * 16 + r) * 40 + quad * 8];
#pragma unroll
      for (int nt = 0; nt < 4; ++nt)
        oacc[f][nt] = __builtin_amdgcn_mfma_f32_16x16x32_bf16(pf, vf[nt], oacc[f][nt], 0, 0, 0);
      lacc[f] = __builtin_amdgcn_mfma_f32_16x16x32_bf16(pf, onesv, lacc[f], 0, 0, 0);
    }

    cur ^= 1;
  }

#pragma unroll
  for (int f = 0; f < 2; ++f)
#pragma unroll
    for (int i = 0; i < 4; ++i) {
      const int qrow = m0 + f * 16 + quad * 4 + i;
      const float inv_l = 1.0f / lacc[f][i];
#pragma unroll
      for (int nt = 0; nt < 4; ++nt)
        O[base + (size_t)qrow * D_ + nt * 16 + r] = f2bf(oacc[f][nt][i] * inv_l);
    }
}

extern "C" void kernel_launch(void* const* d_in, const int* in_sizes, int n_in,
                              void* d_out, int out_size, void* d_ws, size_t ws_size,
                              hipStream_t stream) {
  (void)in_sizes; (void)n_in; (void)out_size; (void)ws_size;
  const float* x   = (const float*)d_in[0];
  const float* wq  = (const float*)d_in[1];
  const float* wk  = (const float*)d_in[2];
  const float* wvp = (const float*)d_in[3];
  const float* wo  = (const float*)d_in[4];
  const float* w1  = (const float*)d_in[5];
  const float* w2  = (const float*)d_in[6];
  const float* g1  = (const float*)d_in[7];
  const float* g2  = (const float*)d_in[8];
  float* out = (float*)d_out;  // also hosts x2 (f32 residual stream 2)

  u16* ws = (u16*)d_ws;
  const size_t TD = (size_t)M_TOK * D_;  // 4M elems
  u16* h  = ws;            // slot0: h, later o, later t[0]
  u16* q  = ws + 1 * TD;   // slot1
  u16* k  = ws + 2 * TD;   // slot2
  u16* vt = ws + 3 * TD;   // slot3: V^T [bh][dh][s]
  u16* h2 = ws + 4 * TD;   // slot4
  u16* o  = h;
  u16* t  = ws;            // FFN1 out spans slots 0..3

  const dim3 blk(256);
  const dim3 gD(D_ / 128, M_TOK / 128);   // (8, 32)
  const dim3 gF(FF_ / 128, M_TOK / 128);  // (32, 32)

  rmsnorm_k<<<M_TOK, blk, 0, stream>>>(x, g1, h);
  gemm_bt_k<0, u16><<<gD, blk, 0, stream>>>(h, wq, nullptr, q, D_, D_);
  gemm_bt_k<0, u16><<<gD, blk, 0, stream>>>(h, wk, nullptr, k, D_, D_);
  gemm_bt_k<3, u16><<<gD, blk, 0, stream>>>(h, wvp, nullptr, vt, D_, D_);  // V^T store
  attn_k<<<dim3(S_ / 128, B_ * H_), blk, 0, stream>>>(q, k, vt, o);
  gemm_bt_k<1, float><<<gD, blk, 0, stream>>>(o, wo, x, out, D_, D_);      // x2 -> d_out (f32)
  rmsnorm_k<<<M_TOK, blk, 0, stream>>>(out, g2, h2);
  gemm_bt_k<2, u16><<<gF, blk, 0, stream>>>(h2, w1, nullptr, t, FF_, D_);
  gemm_bt_k<1, float><<<gD, blk, 0, stream>>>(t, w2, out, out, D_, FF_);   // out = t@w2^T + x2
}

// Round 11
// 499.670 us; speedup vs baseline: 1.4861x; 1.2330x over previous
//
#include <hip/hip_runtime.h>
#include <cstdint>

#define B_ 2
#define S_ 2048
#define D_ 1024
#define H_ 16
#define DH_ 64
#define FF_ 4096
#define M_TOK (B_ * S_)  // 4096 token rows

typedef __attribute__((ext_vector_type(8))) short short8;
typedef __attribute__((ext_vector_type(4))) float f32x4;
typedef __attribute__((ext_vector_type(4))) unsigned short us4;

typedef unsigned short u16;

__device__ __forceinline__ float bf2f(u16 u) {
  union { uint32_t u; float f; } x;
  x.u = ((uint32_t)u) << 16;
  return x.f;
}
__device__ __forceinline__ u16 f2bf(float f) {
  union { float f; uint32_t u; } x;
  x.f = f;
  uint32_t r = x.u + 0x7FFFu + ((x.u >> 16) & 1u);  // RNE
  return (u16)(r >> 16);
}

// async global->LDS, 16B per lane: LDS dest = wave-uniform base + lane*16 (m97-verified).
__device__ __forceinline__ void gl_lds16(const void* g, void* l) {
  __builtin_amdgcn_global_load_lds(
      (const __attribute__((address_space(1))) uint32_t*)(uintptr_t)g,
      (__attribute__((address_space(3))) uint32_t*)(uintptr_t)l, 16, 0, 0);
}

// ---------------- fused f32->bf16 weight convert: wqkv(3M) wob(1M) w1b(4M) w2b(4M) ----------------
#define MEG 1048576
__global__ __launch_bounds__(256) void cvt_all_k(const float* __restrict__ wq, const float* __restrict__ wk,
                                                 const float* __restrict__ wv, const float* __restrict__ wo,
                                                 const float* __restrict__ w1, const float* __restrict__ w2,
                                                 u16* __restrict__ wqkv, u16* __restrict__ wob,
                                                 u16* __restrict__ w1b, u16* __restrict__ w2b) {
  const int n = (blockIdx.x * 256 + threadIdx.x) * 4;  // elem index, total 12M
  const float* src;
  u16* dst;
  int off;
  if (n < 3 * MEG) {
    dst = wqkv; off = n;
    src = (n < MEG) ? wq + n : (n < 2 * MEG ? wk + (n - MEG) : wv + (n - 2 * MEG));
  } else if (n < 4 * MEG) {
    dst = wob; off = n - 3 * MEG; src = wo + off;
  } else if (n < 8 * MEG) {
    dst = w1b; off = n - 4 * MEG; src = w1 + off;
  } else {
    dst = w2b; off = n - 8 * MEG; src = w2 + off;
  }
  const float4 v = *(const float4*)src;
  us4 o;
  o[0] = f2bf(v.x); o[1] = f2bf(v.y); o[2] = f2bf(v.z); o[3] = f2bf(v.w);
  *(us4*)&dst[off] = o;
}

// ---------------- f32 copy (residual seed for WO atomics) ----------------
__global__ __launch_bounds__(256) void copyf_k(const float* __restrict__ src, float* __restrict__ dst) {
  const int i = (blockIdx.x * 256 + threadIdx.x) * 4;
  *(float4*)&dst[i] = *(const float4*)&src[i];
}

// ---------------- RMSNorm: one block per token row (f32 in, bf16 out) ----------------
__global__ __launch_bounds__(256) void rmsnorm_k(const float* __restrict__ X,
                                                 const float* __restrict__ G,
                                                 u16* __restrict__ Hout) {
  const int row = blockIdx.x;
  const int tid = threadIdx.x;
  const float4 xx = *(const float4*)&X[(size_t)row * D_ + tid * 4];
  float v[4] = {xx.x, xx.y, xx.z, xx.w};
  float s = 0.f;
#pragma unroll
  for (int i = 0; i < 4; ++i) s += v[i] * v[i];
#pragma unroll
  for (int d = 1; d < 64; d <<= 1) s += __shfl_xor(s, d);
  __shared__ float red[4];
  if ((tid & 63) == 0) red[tid >> 6] = s;
  __syncthreads();
  s = red[0] + red[1] + red[2] + red[3];
  const float scale = rsqrtf(s * (1.0f / (float)D_) + 1e-5f);
  const float4 gg = *(const float4*)&G[tid * 4];
  us4 o;
  o[0] = f2bf(v[0] * scale * gg.x);
  o[1] = f2bf(v[1] * scale * gg.y);
  o[2] = f2bf(v[2] * scale * gg.z);
  o[3] = f2bf(v[3] * scale * gg.w);
  *(us4*)&Hout[(size_t)row * D_ + tid * 4] = o;
}

// ---------------- m97-style GEMM: C = A(bf16)[M,K] * W(bf16)[N,K]^T, 128x128, BK=32 ----------------
// global_load_lds staging, unpadded LSTR=32. MODE 2: gelu -> C0 bf16 (stride N).
// MODE 4: merged QKV -> C0=q, C1=k (stride 1024), C2=vt [bh][dh][s].
template <int MODE>
__global__ __launch_bounds__(256) void gemm_bt_k(const u16* __restrict__ A,
                                                 const u16* __restrict__ W,
                                                 u16* __restrict__ C0, u16* __restrict__ C1,
                                                 u16* __restrict__ C2, int N, int K) {
  __shared__ alignas(16) u16 As[128 * 32];
  __shared__ alignas(16) u16 Bs[128 * 32];
  const int tid = threadIdx.x;
  const int wv = tid >> 6, lane = tid & 63;
  const int r = lane & 15, quad = lane >> 4;
  const int bm = blockIdx.y * 128, bn = blockIdx.x * 128;
  const int row0 = (wv >> 1) * 64, col0 = (wv & 1) * 64;

  f32x4 acc[4][4] = {};

  for (int k0 = 0; k0 < K; k0 += 32) {
#pragma unroll
    for (int jj = 0; jj < 2; ++jj) {
      const int c = wv * 128 + jj * 64 + lane;  // chunk 0..511
      const int row = c >> 2, g = c & 3;
      const int l0 = (wv * 128 + jj * 64) * 8;  // wave-uniform LDS base (u16 idx)
      gl_lds16(&A[(size_t)(bm + row) * K + k0 + g * 8], &As[l0]);
      gl_lds16(&W[(size_t)(bn + row) * K + k0 + g * 8], &Bs[l0]);
    }
    __syncthreads();
    short8 af[4], bf[4];
#pragma unroll
    for (int mt = 0; mt < 4; ++mt)
      af[mt] = *(const short8*)&As[(row0 + mt * 16 + r) * 32 + quad * 8];
#pragma unroll
    for (int nt = 0; nt < 4; ++nt)
      bf[nt] = *(const short8*)&Bs[(col0 + nt * 16 + r) * 32 + quad * 8];
#pragma unroll
    for (int mt = 0; mt < 4; ++mt)
#pragma unroll
      for (int nt = 0; nt < 4; ++nt)
        acc[mt][nt] = __builtin_amdgcn_mfma_f32_16x16x32_bf16(af[mt], bf[nt], acc[mt][nt], 0, 0, 0);
    __syncthreads();
  }

  if constexpr (MODE == 2) {
#pragma unroll
    for (int mt = 0; mt < 4; ++mt)
#pragma unroll
      for (int nt = 0; nt < 4; ++nt)
#pragma unroll
        for (int i = 0; i < 4; ++i) {
          const int grow = bm + row0 + mt * 16 + quad * 4 + i;
          const int gcol = bn + col0 + nt * 16 + r;
          float v = acc[mt][nt][i];
          v = 0.5f * v * (1.0f + erff(v * 0.70710678118f));
          C0[(size_t)grow * N + gcol] = f2bf(v);
        }
  } else {  // MODE 4: QKV scatter
#pragma unroll
    for (int mt = 0; mt < 4; ++mt) {
      const int grow0 = bm + row0 + mt * 16 + quad * 4;
#pragma unroll
      for (int nt = 0; nt < 4; ++nt) {
        const int gcol = bn + col0 + nt * 16 + r;
        if (gcol < 2048) {
          u16* dst = (gcol < 1024) ? C0 : C1;
          const int cc = gcol & 1023;
#pragma unroll
          for (int i = 0; i < 4; ++i)
            dst[(size_t)(grow0 + i) * 1024 + cc] = f2bf(acc[mt][nt][i]);
        } else {
          const int vcol = gcol - 2048;  // h = vcol>>6, dh = vcol&63; b = grow0>>11, s = grow0&2047
          us4 o;
#pragma unroll
          for (int i = 0; i < 4; ++i) o[i] = f2bf(acc[mt][nt][i]);
          const size_t addr =
              ((size_t)((grow0 >> 11) * 16 + (vcol >> 6)) * 64 + (vcol & 63)) * 2048 + (grow0 & 2047);
          *(us4*)&C2[addr] = o;
        }
      }
    }
  }
}

// ---------------- split-K GEMM: C(f32) += A(bf16) * W(bf16)^T over K-slice, atomic epilogue ----------------
__global__ __launch_bounds__(256) void gemm_sk_k(const u16* __restrict__ A,
                                                 const u16* __restrict__ W,
                                                 float* __restrict__ C, int N, int K, int KS) {
  __shared__ alignas(16) u16 As[128 * 32];
  __shared__ alignas(16) u16 Bs[128 * 32];
  const int tid = threadIdx.x;
  const int wv = tid >> 6, lane = tid & 63;
  const int r = lane & 15, quad = lane >> 4;
  const int bm = blockIdx.y * 128, bn = blockIdx.x * 128;
  const int row0 = (wv >> 1) * 64, col0 = (wv & 1) * 64;
  const int koff = blockIdx.z * KS;

  f32x4 acc[4][4] = {};

  for (int k0 = koff; k0 < koff + KS; k0 += 32) {
#pragma unroll
    for (int jj = 0; jj < 2; ++jj) {
      const int c = wv * 128 + jj * 64 + lane;
      const int row = c >> 2, g = c & 3;
      const int l0 = (wv * 128 + jj * 64) * 8;
      gl_lds16(&A[(size_t)(bm + row) * K + k0 + g * 8], &As[l0]);
      gl_lds16(&W[(size_t)(bn + row) * K + k0 + g * 8], &Bs[l0]);
    }
    __syncthreads();
    short8 af[4], bf[4];
#pragma unroll
    for (int mt = 0; mt < 4; ++mt)
      af[mt] = *(const short8*)&As[(row0 + mt * 16 + r) * 32 + quad * 8];
#pragma unroll
    for (int nt = 0; nt < 4; ++nt)
      bf[nt] = *(const short8*)&Bs[(col0 + nt * 16 + r) * 32 + quad * 8];
#pragma unroll
    for (int mt = 0; mt < 4; ++mt)
#pragma unroll
      for (int nt = 0; nt < 4; ++nt)
        acc[mt][nt] = __builtin_amdgcn_mfma_f32_16x16x32_bf16(af[mt], bf[nt], acc[mt][nt], 0, 0, 0);
    __syncthreads();
  }

#pragma unroll
  for (int mt = 0; mt < 4; ++mt)
#pragma unroll
    for (int nt = 0; nt < 4; ++nt)
#pragma unroll
      for (int i = 0; i < 4; ++i) {
        const int grow = bm + row0 + mt * 16 + quad * 4 + i;
        const int gcol = bn + col0 + nt * 16 + r;
        atomicAdd(&C[(size_t)grow * N + gcol], acc[mt][nt][i]);
      }
}

// ---------------- Flash attention v4 (unchanged from round 10) ----------------
#define SCL 0.18033688011112042f  /* 0.125 * log2(e) */
__global__ __launch_bounds__(256, 2) void attn_k(const u16* __restrict__ Q,
                                                 const u16* __restrict__ Kx,
                                                 const u16* __restrict__ VT,
                                                 u16* __restrict__ O) {
  __shared__ alignas(16) u16 Ks[2][32 * 72];
  __shared__ alignas(16) u16 Vs[2][64 * 40];
  __shared__ alignas(16) u16 Ps[4][32 * 40];

  const int tid = threadIdx.x;
  const int wv = tid >> 6, lane = tid & 63;
  const int r = lane & 15, quad = lane >> 4;
  const int bh = blockIdx.y;
  const int b = bh >> 4, hh = bh & 15;
  const int bx = 15 - (int)blockIdx.x;  // heavy blocks first
  const int qbase = bx * 128;
  const int m0 = qbase + wv * 32;
  const size_t base = (size_t)b * S_ * D_ + (size_t)hh * DH_;
  const u16* Qb = Q + base;
  const u16* Kb = Kx + base;
  const u16* VTb = VT + (size_t)bh * 64 * 2048;
  u16* Psw = &Ps[wv][0];

  short8 qf[2][2];
#pragma unroll
  for (int f = 0; f < 2; ++f) {
    qf[f][0] = *(const short8*)&Qb[(size_t)(m0 + f * 16 + r) * D_ + quad * 8];
    qf[f][1] = *(const short8*)&Qb[(size_t)(m0 + f * 16 + r) * D_ + 32 + quad * 8];
  }

  short8 onesv;
#pragma unroll
  for (int e = 0; e < 8; ++e) onesv[e] = (short)0x3F80;

  f32x4 oacc[2][4] = {};
  f32x4 lacc[2] = {};

  const int niter = 4 * bx + 4;
  const int krow = tid >> 3, kg = tid & 7;
  const int vrow = tid >> 2, vg = tid & 3;

  *(short8*)&Ks[0][krow * 72 + kg * 8] = *(const short8*)&Kb[(size_t)krow * D_ + kg * 8];
  *(short8*)&Vs[0][vrow * 40 + vg * 8] = *(const short8*)&VTb[(size_t)vrow * 2048 + vg * 8];

  int cur = 0;
  for (int it = 0; it < niter; ++it) {
    const int j0 = it * 32;
    __syncthreads();

    if (it + 1 < niter) {
      const int j1 = j0 + 32;
      *(short8*)&Ks[cur ^ 1][krow * 72 + kg * 8] =
          *(const short8*)&Kb[(size_t)(j1 + krow) * D_ + kg * 8];
      *(short8*)&Vs[cur ^ 1][vrow * 40 + vg * 8] =
          *(const short8*)&VTb[(size_t)vrow * 2048 + j1 + vg * 8];
    }

    f32x4 z[2][2];
#pragma unroll
    for (int kt = 0; kt < 2; ++kt) {
      const short8 kf0 = *(const short8*)&Ks[cur][(kt * 16 + r) * 72 + quad * 8];
      const short8 kf1 = *(const short8*)&Ks[cur][(kt * 16 + r) * 72 + 32 + quad * 8];
#pragma unroll
      for (int f = 0; f < 2; ++f) {
        f32x4 zz = {};
        zz = __builtin_amdgcn_mfma_f32_16x16x32_bf16(qf[f][0], kf0, zz, 0, 0, 0);
        zz = __builtin_amdgcn_mfma_f32_16x16x32_bf16(qf[f][1], kf1, zz, 0, 0, 0);
        z[f][kt] = zz;
      }
    }

    const bool masked = (j0 + 31 > m0);
#pragma unroll
    for (int f = 0; f < 2; ++f)
#pragma unroll
      for (int i = 0; i < 4; ++i) {
        const int qrow = m0 + f * 16 + quad * 4 + i;
        float v0 = z[f][0][i] * SCL;
        float v1 = z[f][1][i] * SCL;
        if (masked) {
          if (j0 + r > qrow) v0 = -128.f;
          if (j0 + 16 + r > qrow) v1 = -128.f;
        }
        Psw[(f * 16 + quad * 4 + i) * 40 + r] = f2bf(exp2f(v0));
        Psw[(f * 16 + quad * 4 + i) * 40 + 16 + r] = f2bf(exp2f(v1));
      }

    asm volatile("s_waitcnt lgkmcnt(0)" ::: "memory");

    short8 vf[4];
#pragma unroll
    for (int nt = 0; nt < 4; ++nt)
      vf[nt] = *(const short8*)&Vs[cur][(nt * 16 + r) * 40 + quad * 8];
#pragma unroll
    for (int f = 0; f < 2; ++f) {
      const short8 pf = *(const short8*)&Psw[(f * 16 + r) * 40 + quad * 8];
#pragma unroll
      for (int nt = 0; nt < 4; ++nt)
        oacc[f][nt] = __builtin_amdgcn_mfma_f32_16x16x32_bf16(pf, vf[nt], oacc[f][nt], 0, 0, 0);
      lacc[f] = __builtin_amdgcn_mfma_f32_16x16x32_bf16(pf, onesv, lacc[f], 0, 0, 0);
    }

    cur ^= 1;
  }

#pragma unroll
  for (int f = 0; f < 2; ++f)
#pragma unroll
    for (int i = 0; i < 4; ++i) {
      const int qrow = m0 + f * 16 + quad * 4 + i;
      const float inv_l = 1.0f / lacc[f][i];
#pragma unroll
      for (int nt = 0; nt < 4; ++nt)
        O[base + (size_t)qrow * D_ + nt * 16 + r] = f2bf(oacc[f][nt][i] * inv_l);
    }
}

extern "C" void kernel_launch(void* const* d_in, const int* in_sizes, int n_in,
                              void* d_out, int out_size, void* d_ws, size_t ws_size,
                              hipStream_t stream) {
  (void)in_sizes; (void)n_in; (void)out_size; (void)ws_size;
  const float* x   = (const float*)d_in[0];
  const float* wq  = (const float*)d_in[1];
  const float* wk  = (const float*)d_in[2];
  const float* wvp = (const float*)d_in[3];
  const float* wo  = (const float*)d_in[4];
  const float* w1  = (const float*)d_in[5];
  const float* w2  = (const float*)d_in[6];
  const float* g1  = (const float*)d_in[7];
  const float* g2  = (const float*)d_in[8];
  float* out = (float*)d_out;  // hosts x2 then the final output (f32)

  u16* ws = (u16*)d_ws;
  const size_t TD = (size_t)M_TOK * D_;  // 4M elems
  u16* h   = ws;            // slot0: h, later o, later t[0]
  u16* q   = ws + 1 * TD;   // slot1
  u16* k   = ws + 2 * TD;   // slot2
  u16* vt  = ws + 3 * TD;   // slot3: V^T [bh][dh][s]
  u16* h2  = ws + 4 * TD;   // slot4
  u16* o   = h;
  u16* t   = ws;            // FFN1 out spans slots 0..3
  // bf16 weights after slot 5 (12.5M elems = 25 MB; total ws 65 MB)
  u16* wqkv = ws + 5 * TD;
  u16* wob  = wqkv + 3 * MEG;
  u16* w1b  = wob + 1 * MEG;
  u16* w2b  = w1b + 4 * MEG;

  const dim3 blk(256);

  cvt_all_k<<<12288, blk, 0, stream>>>(wq, wk, wvp, wo, w1, w2, wqkv, wob, w1b, w2b);
  rmsnorm_k<<<M_TOK, blk, 0, stream>>>(x, g1, h);
  gemm_bt_k<4><<<dim3(24, 32), blk, 0, stream>>>(h, wqkv, q, k, vt, 3072, 1024);
  attn_k<<<dim3(S_ / 128, B_ * H_), blk, 0, stream>>>(q, k, vt, o);
  copyf_k<<<4096, blk, 0, stream>>>(x, out);                                   // seed x2 = x
  gemm_sk_k<<<dim3(8, 32, 4), blk, 0, stream>>>(o, wob, out, 1024, 1024, 256); // x2 += o@wo^T
  rmsnorm_k<<<M_TOK, blk, 0, stream>>>(out, g2, h2);
  gemm_bt_k<2><<<dim3(32, 32), blk, 0, stream>>>(h2, w1b, t, nullptr, nullptr, 4096, 1024);
  gemm_sk_k<<<dim3(8, 32, 4), blk, 0, stream>>>(t, w2b, out, 1024, 4096, 1024); // out += t@w2^T
}

// Round 12
// 459.468 us; speedup vs baseline: 1.6161x; 1.0875x over previous
//
#include <hip/hip_runtime.h>
#include <cstdint>

#define B_ 2
#define S_ 2048
#define D_ 1024
#define H_ 16
#define DH_ 64
#define FF_ 4096
#define M_TOK (B_ * S_)  // 4096 token rows

typedef __attribute__((ext_vector_type(8))) short short8;
typedef __attribute__((ext_vector_type(4))) float f32x4;
typedef __attribute__((ext_vector_type(4))) unsigned short us4;

typedef unsigned short u16;

__device__ __forceinline__ float bf2f(u16 u) {
  union { uint32_t u; float f; } x;
  x.u = ((uint32_t)u) << 16;
  return x.f;
}
__device__ __forceinline__ u16 f2bf(float f) {
  union { float f; uint32_t u; } x;
  x.f = f;
  uint32_t r = x.u + 0x7FFFu + ((x.u >> 16) & 1u);  // RNE
  return (u16)(r >> 16);
}

// async global->LDS, 16B per lane: LDS dest = wave-uniform base + lane*16 (m97-verified).
__device__ __forceinline__ void gl_lds16(const void* g, void* l) {
  __builtin_amdgcn_global_load_lds(
      (const __attribute__((address_space(1))) uint32_t*)(uintptr_t)g,
      (__attribute__((address_space(3))) uint32_t*)(uintptr_t)l, 16, 0, 0);
}

// ---------------- fused f32->bf16 weight convert: wqkv(3M) wob(1M) w1b(4M) w2b(4M) ----------------
#define MEG 1048576
__global__ __launch_bounds__(256) void cvt_all_k(const float* __restrict__ wq, const float* __restrict__ wk,
                                                 const float* __restrict__ wv, const float* __restrict__ wo,
                                                 const float* __restrict__ w1, const float* __restrict__ w2,
                                                 u16* __restrict__ wqkv, u16* __restrict__ wob,
                                                 u16* __restrict__ w1b, u16* __restrict__ w2b) {
  const int n = (blockIdx.x * 256 + threadIdx.x) * 4;
  const float* src;
  u16* dst;
  int off;
  if (n < 3 * MEG) {
    dst = wqkv; off = n;
    src = (n < MEG) ? wq + n : (n < 2 * MEG ? wk + (n - MEG) : wv + (n - 2 * MEG));
  } else if (n < 4 * MEG) {
    dst = wob; off = n - 3 * MEG; src = wo + off;
  } else if (n < 8 * MEG) {
    dst = w1b; off = n - 4 * MEG; src = w1 + off;
  } else {
    dst = w2b; off = n - 8 * MEG; src = w2 + off;
  }
  const float4 v = *(const float4*)src;
  us4 o;
  o[0] = f2bf(v.x); o[1] = f2bf(v.y); o[2] = f2bf(v.z); o[3] = f2bf(v.w);
  *(us4*)&dst[off] = o;
}

// ---------------- zero-init: Of (4M f32 in d_out) + l (64K f32) ----------------
__global__ __launch_bounds__(256) void zero_k(float* __restrict__ Of, float* __restrict__ L) {
  const int i = (blockIdx.x * 256 + threadIdx.x) * 4;
  if (i < 4 * MEG) { *(float4*)&Of[i] = float4{0.f, 0.f, 0.f, 0.f}; }
  else { *(float4*)&L[i - 4 * MEG] = float4{0.f, 0.f, 0.f, 0.f}; }
}

// ---------------- normalize: o(bf16) = Of / l ----------------
__global__ __launch_bounds__(256) void norm_o_k(const float* __restrict__ Of, const float* __restrict__ L,
                                                u16* __restrict__ O) {
  const int row = blockIdx.x;  // token
  const int tid = threadIdx.x;
  const int col = tid * 4;
  const int hh = col >> 6;
  const float lv = L[(size_t)((row >> 11) * 16 + hh) * 2048 + (row & 2047)];
  const float inv = 1.0f / lv;
  const float4 v = *(const float4*)&Of[(size_t)row * D_ + col];
  us4 o;
  o[0] = f2bf(v.x * inv); o[1] = f2bf(v.y * inv);
  o[2] = f2bf(v.z * inv); o[3] = f2bf(v.w * inv);
  *(us4*)&O[(size_t)row * D_ + col] = o;
}

// ---------------- f32 copy (residual seed for WO atomics) ----------------
__global__ __launch_bounds__(256) void copyf_k(const float* __restrict__ src, float* __restrict__ dst) {
  const int i = (blockIdx.x * 256 + threadIdx.x) * 4;
  *(float4*)&dst[i] = *(const float4*)&src[i];
}

// ---------------- RMSNorm: one block per token row (f32 in, bf16 out) ----------------
__global__ __launch_bounds__(256) void rmsnorm_k(const float* __restrict__ X,
                                                 const float* __restrict__ G,
                                                 u16* __restrict__ Hout) {
  const int row = blockIdx.x;
  const int tid = threadIdx.x;
  const float4 xx = *(const float4*)&X[(size_t)row * D_ + tid * 4];
  float v[4] = {xx.x, xx.y, xx.z, xx.w};
  float s = 0.f;
#pragma unroll
  for (int i = 0; i < 4; ++i) s += v[i] * v[i];
#pragma unroll
  for (int d = 1; d < 64; d <<= 1) s += __shfl_xor(s, d);
  __shared__ float red[4];
  if ((tid & 63) == 0) red[tid >> 6] = s;
  __syncthreads();
  s = red[0] + red[1] + red[2] + red[3];
  const float scale = rsqrtf(s * (1.0f / (float)D_) + 1e-5f);
  const float4 gg = *(const float4*)&G[tid * 4];
  us4 o;
  o[0] = f2bf(v[0] * scale * gg.x);
  o[1] = f2bf(v[1] * scale * gg.y);
  o[2] = f2bf(v[2] * scale * gg.z);
  o[3] = f2bf(v[3] * scale * gg.w);
  *(us4*)&Hout[(size_t)row * D_ + tid * 4] = o;
}

// ---------------- m97-style GEMM (unchanged from round 11) ----------------
template <int MODE>
__global__ __launch_bounds__(256) void gemm_bt_k(const u16* __restrict__ A,
                                                 const u16* __restrict__ W,
                                                 u16* __restrict__ C0, u16* __restrict__ C1,
                                                 u16* __restrict__ C2, int N, int K) {
  __shared__ alignas(16) u16 As[128 * 32];
  __shared__ alignas(16) u16 Bs[128 * 32];
  const int tid = threadIdx.x;
  const int wv = tid >> 6, lane = tid & 63;
  const int r = lane & 15, quad = lane >> 4;
  const int bm = blockIdx.y * 128, bn = blockIdx.x * 128;
  const int row0 = (wv >> 1) * 64, col0 = (wv & 1) * 64;

  f32x4 acc[4][4] = {};

  for (int k0 = 0; k0 < K; k0 += 32) {
#pragma unroll
    for (int jj = 0; jj < 2; ++jj) {
      const int c = wv * 128 + jj * 64 + lane;
      const int row = c >> 2, g = c & 3;
      const int l0 = (wv * 128 + jj * 64) * 8;
      gl_lds16(&A[(size_t)(bm + row) * K + k0 + g * 8], &As[l0]);
      gl_lds16(&W[(size_t)(bn + row) * K + k0 + g * 8], &Bs[l0]);
    }
    __syncthreads();
    short8 af[4], bf[4];
#pragma unroll
    for (int mt = 0; mt < 4; ++mt)
      af[mt] = *(const short8*)&As[(row0 + mt * 16 + r) * 32 + quad * 8];
#pragma unroll
    for (int nt = 0; nt < 4; ++nt)
      bf[nt] = *(const short8*)&Bs[(col0 + nt * 16 + r) * 32 + quad * 8];
#pragma unroll
    for (int mt = 0; mt < 4; ++mt)
#pragma unroll
      for (int nt = 0; nt < 4; ++nt)
        acc[mt][nt] = __builtin_amdgcn_mfma_f32_16x16x32_bf16(af[mt], bf[nt], acc[mt][nt], 0, 0, 0);
    __syncthreads();
  }

  if constexpr (MODE == 2) {
#pragma unroll
    for (int mt = 0; mt < 4; ++mt)
#pragma unroll
      for (int nt = 0; nt < 4; ++nt)
#pragma unroll
        for (int i = 0; i < 4; ++i) {
          const int grow = bm + row0 + mt * 16 + quad * 4 + i;
          const int gcol = bn + col0 + nt * 16 + r;
          float v = acc[mt][nt][i];
          v = 0.5f * v * (1.0f + erff(v * 0.70710678118f));
          C0[(size_t)grow * N + gcol] = f2bf(v);
        }
  } else {  // MODE 4: QKV scatter
#pragma unroll
    for (int mt = 0; mt < 4; ++mt) {
      const int grow0 = bm + row0 + mt * 16 + quad * 4;
#pragma unroll
      for (int nt = 0; nt < 4; ++nt) {
        const int gcol = bn + col0 + nt * 16 + r;
        if (gcol < 2048) {
          u16* dst = (gcol < 1024) ? C0 : C1;
          const int cc = gcol & 1023;
#pragma unroll
          for (int i = 0; i < 4; ++i)
            dst[(size_t)(grow0 + i) * 1024 + cc] = f2bf(acc[mt][nt][i]);
        } else {
          const int vcol = gcol - 2048;
          us4 o;
#pragma unroll
          for (int i = 0; i < 4; ++i) o[i] = f2bf(acc[mt][nt][i]);
          const size_t addr =
              ((size_t)((grow0 >> 11) * 16 + (vcol >> 6)) * 64 + (vcol & 63)) * 2048 + (grow0 & 2047);
          *(us4*)&C2[addr] = o;
        }
      }
    }
  }
}

// ---------------- split-K GEMM: C(f32) += A * W^T over K-slice, atomic epilogue ----------------
__global__ __launch_bounds__(256) void gemm_sk_k(const u16* __restrict__ A,
                                                 const u16* __restrict__ W,
                                                 float* __restrict__ C, int N, int K, int KS) {
  __shared__ alignas(16) u16 As[128 * 32];
  __shared__ alignas(16) u16 Bs[128 * 32];
  const int tid = threadIdx.x;
  const int wv = tid >> 6, lane = tid & 63;
  const int r = lane & 15, quad = lane >> 4;
  const int bm = blockIdx.y * 128, bn = blockIdx.x * 128;
  const int row0 = (wv >> 1) * 64, col0 = (wv & 1) * 64;
  const int koff = blockIdx.z * KS;

  f32x4 acc[4][4] = {};

  for (int k0 = koff; k0 < koff + KS; k0 += 32) {
#pragma unroll
    for (int jj = 0; jj < 2; ++jj) {
      const int c = wv * 128 + jj * 64 + lane;
      const int row = c >> 2, g = c & 3;
      const int l0 = (wv * 128 + jj * 64) * 8;
      gl_lds16(&A[(size_t)(bm + row) * K + k0 + g * 8], &As[l0]);
      gl_lds16(&W[(size_t)(bn + row) * K + k0 + g * 8], &Bs[l0]);
    }
    __syncthreads();
    short8 af[4], bf[4];
#pragma unroll
    for (int mt = 0; mt < 4; ++mt)
      af[mt] = *(const short8*)&As[(row0 + mt * 16 + r) * 32 + quad * 8];
#pragma unroll
    for (int nt = 0; nt < 4; ++nt)
      bf[nt] = *(const short8*)&Bs[(col0 + nt * 16 + r) * 32 + quad * 8];
#pragma unroll
    for (int mt = 0; mt < 4; ++mt)
#pragma unroll
      for (int nt = 0; nt < 4; ++nt)
        acc[mt][nt] = __builtin_amdgcn_mfma_f32_16x16x32_bf16(af[mt], bf[nt], acc[mt][nt], 0, 0, 0);
    __syncthreads();
  }

#pragma unroll
  for (int mt = 0; mt < 4; ++mt)
#pragma unroll
    for (int nt = 0; nt < 4; ++nt)
#pragma unroll
      for (int i = 0; i < 4; ++i) {
        const int grow = bm + row0 + mt * 16 + quad * 4 + i;
        const int gcol = bn + col0 + nt * 16 + r;
        atomicAdd(&C[(size_t)grow * N + gcol], acc[mt][nt][i]);
      }
}

// ---------------- Flash attention v5: key-split blocks, additive partials (fixed-max) ----------------
// Block = (q-tile 128 rows, 512-key chunk) x 32 bh = 1280 blocks (5/CU). Partial O (unnorm, f32)
// and l accumulate via atomicAdd; norm_o_k divides at the end.
#define SCL 0.18033688011112042f  /* 0.125 * log2(e) */
__global__ __launch_bounds__(256, 2) void attn_k(const u16* __restrict__ Q,
                                                 const u16* __restrict__ Kx,
                                                 const u16* __restrict__ VT,
                                                 float* __restrict__ Of, float* __restrict__ L) {
  __shared__ alignas(16) u16 Ks[2][32 * 72];
  __shared__ alignas(16) u16 Vs[2][64 * 40];
  __shared__ alignas(16) u16 Ps[4][32 * 40];

  const int tid = threadIdx.x;
  const int wv = tid >> 6, lane = tid & 63;
  const int r = lane & 15, quad = lane >> 4;
  const int bh = blockIdx.y;
  const int b = bh >> 4, hh = bh & 15;

  // decode (bx, chunk) from flattened 40-entry list, heavy-ish first
  int id = 39 - (int)blockIdx.x;
  int bx = 0;
  for (;;) {
    const int nb = (bx >> 2) + 1;
    if (id < nb) break;
    id -= nb;
    ++bx;
  }
  const int c = id;
  const int j0base = c * 512;
  const int niter = (min(bx * 128 + 128, j0base + 512) - j0base) >> 5;

  const int qbase = bx * 128;
  const int m0 = qbase + wv * 32;
  const size_t base = (size_t)b * S_ * D_ + (size_t)hh * DH_;
  const u16* Qb = Q + base;
  const u16* Kb = Kx + base;
  const u16* VTb = VT + (size_t)bh * 64 * 2048;
  u16* Psw = &Ps[wv][0];

  short8 qf[2][2];
#pragma unroll
  for (int f = 0; f < 2; ++f) {
    qf[f][0] = *(const short8*)&Qb[(size_t)(m0 + f * 16 + r) * D_ + quad * 8];
    qf[f][1] = *(const short8*)&Qb[(size_t)(m0 + f * 16 + r) * D_ + 32 + quad * 8];
  }

  short8 onesv;
#pragma unroll
  for (int e = 0; e < 8; ++e) onesv[e] = (short)0x3F80;

  f32x4 oacc[2][4] = {};
  f32x4 lacc[2] = {};

  const int krow = tid >> 3, kg = tid & 7;
  const int vrow = tid >> 2, vg = tid & 3;

  *(short8*)&Ks[0][krow * 72 + kg * 8] = *(const short8*)&Kb[(size_t)(j0base + krow) * D_ + kg * 8];
  *(short8*)&Vs[0][vrow * 40 + vg * 8] = *(const short8*)&VTb[(size_t)vrow * 2048 + j0base + vg * 8];

  int cur = 0;
  for (int it = 0; it < niter; ++it) {
    const int j0 = j0base + it * 32;
    __syncthreads();

    if (it + 1 < niter) {
      const int j1 = j0 + 32;
      *(short8*)&Ks[cur ^ 1][krow * 72 + kg * 8] =
          *(const short8*)&Kb[(size_t)(j1 + krow) * D_ + kg * 8];
      *(short8*)&Vs[cur ^ 1][vrow * 40 + vg * 8] =
          *(const short8*)&VTb[(size_t)vrow * 2048 + j1 + vg * 8];
    }

    f32x4 z[2][2];
#pragma unroll
    for (int kt = 0; kt < 2; ++kt) {
      const short8 kf0 = *(const short8*)&Ks[cur][(kt * 16 + r) * 72 + quad * 8];
      const short8 kf1 = *(const short8*)&Ks[cur][(kt * 16 + r) * 72 + 32 + quad * 8];
#pragma unroll
      for (int f = 0; f < 2; ++f) {
        f32x4 zz = {};
        zz = __builtin_amdgcn_mfma_f32_16x16x32_bf16(qf[f][0], kf0, zz, 0, 0, 0);
        zz = __builtin_amdgcn_mfma_f32_16x16x32_bf16(qf[f][1], kf1, zz, 0, 0, 0);
        z[f][kt] = zz;
      }
    }

    const bool masked = (j0 + 31 > m0);
#pragma unroll
    for (int f = 0; f < 2; ++f)
#pragma unroll
      for (int i = 0; i < 4; ++i) {
        const int qrow = m0 + f * 16 + quad * 4 + i;
        float v0 = z[f][0][i] * SCL;
        float v1 = z[f][1][i] * SCL;
        if (masked) {
          if (j0 + r > qrow) v0 = -128.f;
          if (j0 + 16 + r > qrow) v1 = -128.f;
        }
        Psw[(f * 16 + quad * 4 + i) * 40 + r] = f2bf(exp2f(v0));
        Psw[(f * 16 + quad * 4 + i) * 40 + 16 + r] = f2bf(exp2f(v1));
      }

    asm volatile("s_waitcnt lgkmcnt(0)" ::: "memory");

    short8 vf[4];
#pragma unroll
    for (int nt = 0; nt < 4; ++nt)
      vf[nt] = *(const short8*)&Vs[cur][(nt * 16 + r) * 40 + quad * 8];
#pragma unroll
    for (int f = 0; f < 2; ++f) {
      const short8 pf = *(const short8*)&Psw[(f * 16 + r) * 40 + quad * 8];
#pragma unroll
      for (int nt = 0; nt < 4; ++nt)
        oacc[f][nt] = __builtin_amdgcn_mfma_f32_16x16x32_bf16(pf, vf[nt], oacc[f][nt], 0, 0, 0);
      lacc[f] = __builtin_amdgcn_mfma_f32_16x16x32_bf16(pf, onesv, lacc[f], 0, 0, 0);
    }

    cur ^= 1;
  }

  // atomic accumulation of unnormalized partials
#pragma unroll
  for (int f = 0; f < 2; ++f) {
#pragma unroll
    for (int i = 0; i < 4; ++i) {
      const int qrow = m0 + f * 16 + quad * 4 + i;
#pragma unroll
      for (int nt = 0; nt < 4; ++nt)
        atomicAdd(&Of[base + (size_t)qrow * D_ + nt * 16 + r], oacc[f][nt][i]);
      if (r == 0) atomicAdd(&L[(size_t)bh * 2048 + qrow], lacc[f][i]);
    }
  }
}

extern "C" void kernel_launch(void* const* d_in, const int* in_sizes, int n_in,
                              void* d_out, int out_size, void* d_ws, size_t ws_size,
                              hipStream_t stream) {
  (void)in_sizes; (void)n_in; (void)out_size; (void)ws_size;
  const float* x   = (const float*)d_in[0];
  const float* wq  = (const float*)d_in[1];
  const float* wk  = (const float*)d_in[2];
  const float* wvp = (const float*)d_in[3];
  const float* wo  = (const float*)d_in[4];
  const float* w1  = (const float*)d_in[5];
  const float* w2  = (const float*)d_in[6];
  const float* g1  = (const float*)d_in[7];
  const float* g2  = (const float*)d_in[8];
  float* out = (float*)d_out;  // Of accumulator, then x2, then final output

  u16* ws = (u16*)d_ws;
  const size_t TD = (size_t)M_TOK * D_;  // 4M elems
  u16* h   = ws;            // slot0: h, later o, later t[0]
  u16* q   = ws + 1 * TD;   // slot1
  u16* k   = ws + 2 * TD;   // slot2
  u16* vt  = ws + 3 * TD;   // slot3: V^T [bh][dh][s]
  u16* h2  = ws + 4 * TD;   // slot4 (l shares its head; h2 written after l is dead)
  float* l = (float*)(ws + 4 * TD);  // 64K f32 = 128K u16
  u16* o   = h;
  u16* t   = ws;            // FFN1 out spans slots 0..3
  u16* wqkv = ws + 5 * TD;
  u16* wob  = wqkv + 3 * MEG;
  u16* w1b  = wob + 1 * MEG;
  u16* w2b  = w1b + 4 * MEG;

  const dim3 blk(256);

  cvt_all_k<<<12288, blk, 0, stream>>>(wq, wk, wvp, wo, w1, w2, wqkv, wob, w1b, w2b);
  zero_k<<<(4 * MEG + 65536) / 1024, blk, 0, stream>>>(out, l);
  rmsnorm_k<<<M_TOK, blk, 0, stream>>>(x, g1, h);
  gemm_bt_k<4><<<dim3(24, 32), blk, 0, stream>>>(h, wqkv, q, k, vt, 3072, 1024);
  attn_k<<<dim3(40, 32), blk, 0, stream>>>(q, k, vt, out, l);
  norm_o_k<<<M_TOK, blk, 0, stream>>>(out, l, o);
  copyf_k<<<4096, blk, 0, stream>>>(x, out);                                    // seed x2 = x
  gemm_sk_k<<<dim3(8, 32, 4), blk, 0, stream>>>(o, wob, out, 1024, 1024, 256);  // x2 += o@wo^T
  rmsnorm_k<<<M_TOK, blk, 0, stream>>>(out, g2, h2);
  gemm_bt_k<2><<<dim3(32, 32), blk, 0, stream>>>(h2, w1b, t, nullptr, nullptr, 4096, 1024);
  gemm_sk_k<<<dim3(8, 32, 4), blk, 0, stream>>>(t, w2b, out, 1024, 4096, 1024);  // out += t@w2^T
}

// Round 13
// 390.289 us; speedup vs baseline: 1.9025x; 1.1772x over previous
//
#include <hip/hip_runtime.h>
#include <cstdint>

#define B_ 2
#define S_ 2048
#define D_ 1024
#define H_ 16
#define DH_ 64
#define FF_ 4096
#define M_TOK (B_ * S_)  // 4096 token rows

typedef __attribute__((ext_vector_type(8))) short short8;
typedef __attribute__((ext_vector_type(4))) float f32x4;
typedef __attribute__((ext_vector_type(4))) unsigned short us4;

typedef unsigned short u16;

__device__ __forceinline__ float bf2f(u16 u) {
  union { uint32_t u; float f; } x;
  x.u = ((uint32_t)u) << 16;
  return x.f;
}
__device__ __forceinline__ u16 f2bf(float f) {
  union { float f; uint32_t u; } x;
  x.f = f;
  uint32_t r = x.u + 0x7FFFu + ((x.u >> 16) & 1u);  // RNE
  return (u16)(r >> 16);
}

// async global->LDS, 16B per lane: LDS dest = wave-uniform base + lane*16 (m97-verified).
__device__ __forceinline__ void gl_lds16(const void* g, void* l) {
  __builtin_amdgcn_global_load_lds(
      (const __attribute__((address_space(1))) uint32_t*)(uintptr_t)g,
      (__attribute__((address_space(3))) uint32_t*)(uintptr_t)l, 16, 0, 0);
}

// ---------------- fused f32->bf16 weight convert: wqkv(3M) wob(1M) w1b(4M) w2b(4M) ----------------
#define MEG 1048576
__global__ __launch_bounds__(256) void cvt_all_k(const float* __restrict__ wq, const float* __restrict__ wk,
                                                 const float* __restrict__ wv, const float* __restrict__ wo,
                                                 const float* __restrict__ w1, const float* __restrict__ w2,
                                                 u16* __restrict__ wqkv, u16* __restrict__ wob,
                                                 u16* __restrict__ w1b, u16* __restrict__ w2b) {
  const int n = (blockIdx.x * 256 + threadIdx.x) * 4;
  const float* src;
  u16* dst;
  int off;
  if (n < 3 * MEG) {
    dst = wqkv; off = n;
    src = (n < MEG) ? wq + n : (n < 2 * MEG ? wk + (n - MEG) : wv + (n - 2 * MEG));
  } else if (n < 4 * MEG) {
    dst = wob; off = n - 3 * MEG; src = wo + off;
  } else if (n < 8 * MEG) {
    dst = w1b; off = n - 4 * MEG; src = w1 + off;
  } else {
    dst = w2b; off = n - 8 * MEG; src = w2 + off;
  }
  const float4 v = *(const float4*)src;
  us4 o;
  o[0] = f2bf(v.x); o[1] = f2bf(v.y); o[2] = f2bf(v.z); o[3] = f2bf(v.w);
  *(us4*)&dst[off] = o;
}

// ---------------- zero-init: Of (4M f32 in d_out) + l (64K f32) ----------------
__global__ __launch_bounds__(256) void zero_k(float* __restrict__ Of, float* __restrict__ L) {
  const int i = (blockIdx.x * 256 + threadIdx.x) * 4;
  if (i < 4 * MEG) { *(float4*)&Of[i] = float4{0.f, 0.f, 0.f, 0.f}; }
  else { *(float4*)&L[i - 4 * MEG] = float4{0.f, 0.f, 0.f, 0.f}; }
}

// ---------------- normalize: o(bf16) = Of / l ----------------
__global__ __launch_bounds__(256) void norm_o_k(const float* __restrict__ Of, const float* __restrict__ L,
                                                u16* __restrict__ O) {
  const int row = blockIdx.x;  // token
  const int tid = threadIdx.x;
  const int col = tid * 4;
  const int hh = col >> 6;
  const float lv = L[(size_t)((row >> 11) * 16 + hh) * 2048 + (row & 2047)];
  const float inv = 1.0f / lv;
  const float4 v = *(const float4*)&Of[(size_t)row * D_ + col];
  us4 o;
  o[0] = f2bf(v.x * inv); o[1] = f2bf(v.y * inv);
  o[2] = f2bf(v.z * inv); o[3] = f2bf(v.w * inv);
  *(us4*)&O[(size_t)row * D_ + col] = o;
}

// ---------------- RMSNorm (pass 1): f32 in, bf16 out ----------------
__global__ __launch_bounds__(256) void rmsnorm_k(const float* __restrict__ X,
                                                 const float* __restrict__ G,
                                                 u16* __restrict__ Hout) {
  const int row = blockIdx.x;
  const int tid = threadIdx.x;
  const float4 xx = *(const float4*)&X[(size_t)row * D_ + tid * 4];
  float v[4] = {xx.x, xx.y, xx.z, xx.w};
  float s = 0.f;
#pragma unroll
  for (int i = 0; i < 4; ++i) s += v[i] * v[i];
#pragma unroll
  for (int d = 1; d < 64; d <<= 1) s += __shfl_xor(s, d);
  __shared__ float red[4];
  if ((tid & 63) == 0) red[tid >> 6] = s;
  __syncthreads();
  s = red[0] + red[1] + red[2] + red[3];
  const float scale = rsqrtf(s * (1.0f / (float)D_) + 1e-5f);
  const float4 gg = *(const float4*)&G[tid * 4];
  us4 o;
  o[0] = f2bf(v[0] * scale * gg.x);
  o[1] = f2bf(v[1] * scale * gg.y);
  o[2] = f2bf(v[2] * scale * gg.z);
  o[3] = f2bf(v[3] * scale * gg.w);
  *(us4*)&Hout[(size_t)row * D_ + tid * 4] = o;
}

// ---------------- fused WO-reduce + residual + RMSNorm: x2 = P0+P1+x; h2 = rmsnorm(x2)*g2 ----------------
__global__ __launch_bounds__(256) void rmsnorm_wo_k(const u16* __restrict__ P0, const u16* __restrict__ P1,
                                                    const float* __restrict__ X, const float* __restrict__ G,
                                                    float* __restrict__ X2, u16* __restrict__ Hout) {
  const int row = blockIdx.x;
  const int tid = threadIdx.x;
  const size_t off = (size_t)row * D_ + tid * 4;
  const us4 p0 = *(const us4*)&P0[off];
  const us4 p1 = *(const us4*)&P1[off];
  const float4 xx = *(const float4*)&X[off];
  float v[4];
  v[0] = bf2f(p0[0]) + bf2f(p1[0]) + xx.x;
  v[1] = bf2f(p0[1]) + bf2f(p1[1]) + xx.y;
  v[2] = bf2f(p0[2]) + bf2f(p1[2]) + xx.z;
  v[3] = bf2f(p0[3]) + bf2f(p1[3]) + xx.w;
  *(float4*)&X2[off] = float4{v[0], v[1], v[2], v[3]};
  float s = 0.f;
#pragma unroll
  for (int i = 0; i < 4; ++i) s += v[i] * v[i];
#pragma unroll
  for (int d = 1; d < 64; d <<= 1) s += __shfl_xor(s, d);
  __shared__ float red[4];
  if ((tid & 63) == 0) red[tid >> 6] = s;
  __syncthreads();
  s = red[0] + red[1] + red[2] + red[3];
  const float scale = rsqrtf(s * (1.0f / (float)D_) + 1e-5f);
  const float4 gg = *(const float4*)&G[tid * 4];
  us4 o;
  o[0] = f2bf(v[0] * scale * gg.x);
  o[1] = f2bf(v[1] * scale * gg.y);
  o[2] = f2bf(v[2] * scale * gg.z);
  o[3] = f2bf(v[3] * scale * gg.w);
  *(us4*)&Hout[off] = o;
}

// ---------------- FFN2 reduce: out = Q0 + Q1 + x2 (in place on d_out) ----------------
__global__ __launch_bounds__(256) void ffn2_red_k(const u16* __restrict__ Q0, const u16* __restrict__ Q1,
                                                  float* __restrict__ OUT) {
  const int i = (blockIdx.x * 256 + threadIdx.x) * 4;
  const us4 a = *(const us4*)&Q0[i];
  const us4 b = *(const us4*)&Q1[i];
  const float4 c = *(const float4*)&OUT[i];
  *(float4*)&OUT[i] = float4{bf2f(a[0]) + bf2f(b[0]) + c.x, bf2f(a[1]) + bf2f(b[1]) + c.y,
                             bf2f(a[2]) + bf2f(b[2]) + c.z, bf2f(a[3]) + bf2f(b[3]) + c.w};
}

// ---------------- m97-style GEMM (MODE 2: gelu store; MODE 4: QKV scatter) ----------------
template <int MODE>
__global__ __launch_bounds__(256) void gemm_bt_k(const u16* __restrict__ A,
                                                 const u16* __restrict__ W,
                                                 u16* __restrict__ C0, u16* __restrict__ C1,
                                                 u16* __restrict__ C2, int N, int K) {
  __shared__ alignas(16) u16 As[128 * 32];
  __shared__ alignas(16) u16 Bs[128 * 32];
  const int tid = threadIdx.x;
  const int wv = tid >> 6, lane = tid & 63;
  const int r = lane & 15, quad = lane >> 4;
  const int bm = blockIdx.y * 128, bn = blockIdx.x * 128;
  const int row0 = (wv >> 1) * 64, col0 = (wv & 1) * 64;

  f32x4 acc[4][4] = {};

  for (int k0 = 0; k0 < K; k0 += 32) {
#pragma unroll
    for (int jj = 0; jj < 2; ++jj) {
      const int c = wv * 128 + jj * 64 + lane;
      const int row = c >> 2, g = c & 3;
      const int l0 = (wv * 128 + jj * 64) * 8;
      gl_lds16(&A[(size_t)(bm + row) * K + k0 + g * 8], &As[l0]);
      gl_lds16(&W[(size_t)(bn + row) * K + k0 + g * 8], &Bs[l0]);
    }
    __syncthreads();
    short8 af[4], bf[4];
#pragma unroll
    for (int mt = 0; mt < 4; ++mt)
      af[mt] = *(const short8*)&As[(row0 + mt * 16 + r) * 32 + quad * 8];
#pragma unroll
    for (int nt = 0; nt < 4; ++nt)
      bf[nt] = *(const short8*)&Bs[(col0 + nt * 16 + r) * 32 + quad * 8];
#pragma unroll
    for (int mt = 0; mt < 4; ++mt)
#pragma unroll
      for (int nt = 0; nt < 4; ++nt)
        acc[mt][nt] = __builtin_amdgcn_mfma_f32_16x16x32_bf16(af[mt], bf[nt], acc[mt][nt], 0, 0, 0);
    __syncthreads();
  }

  if constexpr (MODE == 2) {
#pragma unroll
    for (int mt = 0; mt < 4; ++mt)
#pragma unroll
      for (int nt = 0; nt < 4; ++nt)
#pragma unroll
        for (int i = 0; i < 4; ++i) {
          const int grow = bm + row0 + mt * 16 + quad * 4 + i;
          const int gcol = bn + col0 + nt * 16 + r;
          float v = acc[mt][nt][i];
          v = 0.5f * v * (1.0f + erff(v * 0.70710678118f));
          C0[(size_t)grow * N + gcol] = f2bf(v);
        }
  } else {  // MODE 4: QKV scatter
#pragma unroll
    for (int mt = 0; mt < 4; ++mt) {
      const int grow0 = bm + row0 + mt * 16 + quad * 4;
#pragma unroll
      for (int nt = 0; nt < 4; ++nt) {
        const int gcol = bn + col0 + nt * 16 + r;
        if (gcol < 2048) {
          u16* dst = (gcol < 1024) ? C0 : C1;
          const int cc = gcol & 1023;
#pragma unroll
          for (int i = 0; i < 4; ++i)
            dst[(size_t)(grow0 + i) * 1024 + cc] = f2bf(acc[mt][nt][i]);
        } else {
          const int vcol = gcol - 2048;
          us4 o;
#pragma unroll
          for (int i = 0; i < 4; ++i) o[i] = f2bf(acc[mt][nt][i]);
          const size_t addr =
              ((size_t)((grow0 >> 11) * 16 + (vcol >> 6)) * 64 + (vcol & 63)) * 2048 + (grow0 & 2047);
          *(us4*)&C2[addr] = o;
        }
      }
    }
  }
}

// ---------------- split-K=2 GEMM: slice z writes bf16 partial Pz (plain stores, no atomics) ----------------
__global__ __launch_bounds__(256) void gemm_sk2_k(const u16* __restrict__ A,
                                                  const u16* __restrict__ W,
                                                  u16* __restrict__ P0, u16* __restrict__ P1,
                                                  int N, int K, int KS) {
  __shared__ alignas(16) u16 As[128 * 32];
  __shared__ alignas(16) u16 Bs[128 * 32];
  const int tid = threadIdx.x;
  const int wv = tid >> 6, lane = tid & 63;
  const int r = lane & 15, quad = lane >> 4;
  const int bm = blockIdx.y * 128, bn = blockIdx.x * 128;
  const int row0 = (wv >> 1) * 64, col0 = (wv & 1) * 64;
  const int koff = blockIdx.z * KS;
  u16* P = blockIdx.z ? P1 : P0;

  f32x4 acc[4][4] = {};

  for (int k0 = koff; k0 < koff + KS; k0 += 32) {
#pragma unroll
    for (int jj = 0; jj < 2; ++jj) {
      const int c = wv * 128 + jj * 64 + lane;
      const int row = c >> 2, g = c & 3;
      const int l0 = (wv * 128 + jj * 64) * 8;
      gl_lds16(&A[(size_t)(bm + row) * K + k0 + g * 8], &As[l0]);
      gl_lds16(&W[(size_t)(bn + row) * K + k0 + g * 8], &Bs[l0]);
    }
    __syncthreads();
    short8 af[4], bf[4];
#pragma unroll
    for (int mt = 0; mt < 4; ++mt)
      af[mt] = *(const short8*)&As[(row0 + mt * 16 + r) * 32 + quad * 8];
#pragma unroll
    for (int nt = 0; nt < 4; ++nt)
      bf[nt] = *(const short8*)&Bs[(col0 + nt * 16 + r) * 32 + quad * 8];
#pragma unroll
    for (int mt = 0; mt < 4; ++mt)
#pragma unroll
      for (int nt = 0; nt < 4; ++nt)
        acc[mt][nt] = __builtin_amdgcn_mfma_f32_16x16x32_bf16(af[mt], bf[nt], acc[mt][nt], 0, 0, 0);
    __syncthreads();
  }

#pragma unroll
  for (int mt = 0; mt < 4; ++mt)
#pragma unroll
    for (int nt = 0; nt < 4; ++nt)
#pragma unroll
      for (int i = 0; i < 4; ++i) {
        const int grow = bm + row0 + mt * 16 + quad * 4 + i;
        const int gcol = bn + col0 + nt * 16 + r;
        P[(size_t)grow * N + gcol] = f2bf(acc[mt][nt][i]);
      }
}

// ---------------- Flash attention v5 (unchanged from round 12) ----------------
#define SCL 0.18033688011112042f  /* 0.125 * log2(e) */
__global__ __launch_bounds__(256, 2) void attn_k(const u16* __restrict__ Q,
                                                 const u16* __restrict__ Kx,
                                                 const u16* __restrict__ VT,
                                                 float* __restrict__ Of, float* __restrict__ L) {
  __shared__ alignas(16) u16 Ks[2][32 * 72];
  __shared__ alignas(16) u16 Vs[2][64 * 40];
  __shared__ alignas(16) u16 Ps[4][32 * 40];

  const int tid = threadIdx.x;
  const int wv = tid >> 6, lane = tid & 63;
  const int r = lane & 15, quad = lane >> 4;
  const int bh = blockIdx.y;
  const int b = bh >> 4, hh = bh & 15;

  int id = 39 - (int)blockIdx.x;
  int bx = 0;
  for (;;) {
    const int nb = (bx >> 2) + 1;
    if (id < nb) break;
    id -= nb;
    ++bx;
  }
  const int c = id;
  const int j0base = c * 512;
  const int niter = (min(bx * 128 + 128, j0base + 512) - j0base) >> 5;

  const int qbase = bx * 128;
  const int m0 = qbase + wv * 32;
  const size_t base = (size_t)b * S_ * D_ + (size_t)hh * DH_;
  const u16* Qb = Q + base;
  const u16* Kb = Kx + base;
  const u16* VTb = VT + (size_t)bh * 64 * 2048;
  u16* Psw = &Ps[wv][0];

  short8 qf[2][2];
#pragma unroll
  for (int f = 0; f < 2; ++f) {
    qf[f][0] = *(const short8*)&Qb[(size_t)(m0 + f * 16 + r) * D_ + quad * 8];
    qf[f][1] = *(const short8*)&Qb[(size_t)(m0 + f * 16 + r) * D_ + 32 + quad * 8];
  }

  short8 onesv;
#pragma unroll
  for (int e = 0; e < 8; ++e) onesv[e] = (short)0x3F80;

  f32x4 oacc[2][4] = {};
  f32x4 lacc[2] = {};

  const int krow = tid >> 3, kg = tid & 7;
  const int vrow = tid >> 2, vg = tid & 3;

  *(short8*)&Ks[0][krow * 72 + kg * 8] = *(const short8*)&Kb[(size_t)(j0base + krow) * D_ + kg * 8];
  *(short8*)&Vs[0][vrow * 40 + vg * 8] = *(const short8*)&VTb[(size_t)vrow * 2048 + j0base + vg * 8];

  int cur = 0;
  for (int it = 0; it < niter; ++it) {
    const int j0 = j0base + it * 32;
    __syncthreads();

    if (it + 1 < niter) {
      const int j1 = j0 + 32;
      *(short8*)&Ks[cur ^ 1][krow * 72 + kg * 8] =
          *(const short8*)&Kb[(size_t)(j1 + krow) * D_ + kg * 8];
      *(short8*)&Vs[cur ^ 1][vrow * 40 + vg * 8] =
          *(const short8*)&VTb[(size_t)vrow * 2048 + j1 + vg * 8];
    }

    f32x4 z[2][2];
#pragma unroll
    for (int kt = 0; kt < 2; ++kt) {
      const short8 kf0 = *(const short8*)&Ks[cur][(kt * 16 + r) * 72 + quad * 8];
      const short8 kf1 = *(const short8*)&Ks[cur][(kt * 16 + r) * 72 + 32 + quad * 8];
#pragma unroll
      for (int f = 0; f < 2; ++f) {
        f32x4 zz = {};
        zz = __builtin_amdgcn_mfma_f32_16x16x32_bf16(qf[f][0], kf0, zz, 0, 0, 0);
        zz = __builtin_amdgcn_mfma_f32_16x16x32_bf16(qf[f][1], kf1, zz, 0, 0, 0);
        z[f][kt] = zz;
      }
    }

    const bool masked = (j0 + 31 > m0);
#pragma unroll
    for (int f = 0; f < 2; ++f)
#pragma unroll
      for (int i = 0; i < 4; ++i) {
        const int qrow = m0 + f * 16 + quad * 4 + i;
        float v0 = z[f][0][i] * SCL;
        float v1 = z[f][1][i] * SCL;
        if (masked) {
          if (j0 + r > qrow) v0 = -128.f;
          if (j0 + 16 + r > qrow) v1 = -128.f;
        }
        Psw[(f * 16 + quad * 4 + i) * 40 + r] = f2bf(exp2f(v0));
        Psw[(f * 16 + quad * 4 + i) * 40 + 16 + r] = f2bf(exp2f(v1));
      }

    asm volatile("s_waitcnt lgkmcnt(0)" ::: "memory");

    short8 vf[4];
#pragma unroll
    for (int nt = 0; nt < 4; ++nt)
      vf[nt] = *(const short8*)&Vs[cur][(nt * 16 + r) * 40 + quad * 8];
#pragma unroll
    for (int f = 0; f < 2; ++f) {
      const short8 pf = *(const short8*)&Psw[(f * 16 + r) * 40 + quad * 8];
#pragma unroll
      for (int nt = 0; nt < 4; ++nt)
        oacc[f][nt] = __builtin_amdgcn_mfma_f32_16x16x32_bf16(pf, vf[nt], oacc[f][nt], 0, 0, 0);
      lacc[f] = __builtin_amdgcn_mfma_f32_16x16x32_bf16(pf, onesv, lacc[f], 0, 0, 0);
    }

    cur ^= 1;
  }

#pragma unroll
  for (int f = 0; f < 2; ++f) {
#pragma unroll
    for (int i = 0; i < 4; ++i) {
      const int qrow = m0 + f * 16 + quad * 4 + i;
#pragma unroll
      for (int nt = 0; nt < 4; ++nt)
        atomicAdd(&Of[base + (size_t)qrow * D_ + nt * 16 + r], oacc[f][nt][i]);
      if (r == 0) atomicAdd(&L[(size_t)bh * 2048 + qrow], lacc[f][i]);
    }
  }
}

extern "C" void kernel_launch(void* const* d_in, const int* in_sizes, int n_in,
                              void* d_out, int out_size, void* d_ws, size_t ws_size,
                              hipStream_t stream) {
  (void)in_sizes; (void)n_in; (void)out_size; (void)ws_size;
  const float* x   = (const float*)d_in[0];
  const float* wq  = (const float*)d_in[1];
  const float* wk  = (const float*)d_in[2];
  const float* wvp = (const float*)d_in[3];
  const float* wo  = (const float*)d_in[4];
  const float* w1  = (const float*)d_in[5];
  const float* w2  = (const float*)d_in[6];
  const float* g1  = (const float*)d_in[7];
  const float* g2  = (const float*)d_in[8];
  float* out = (float*)d_out;  // Of accumulator -> x2 -> final output

  u16* ws = (u16*)d_ws;
  const size_t TD = (size_t)M_TOK * D_;  // 4M elems (8 MB)
  u16* h    = ws;            // slot0: h -> o -> t[0]
  u16* q    = ws + 1 * TD;   // slot1: q -> P0 -> t[1]
  u16* k    = ws + 2 * TD;   // slot2: k -> P1 -> t[2]
  u16* vt   = ws + 3 * TD;   // slot3: vt -> t[3]
  u16* h2   = ws + 4 * TD;   // slot4: l (head) -> h2 -> Q0
  float* l  = (float*)(ws + 4 * TD);
  u16* o    = h;
  u16* t    = ws;            // FFN1 out spans slots 0..3
  u16* P0   = q;             // WO partials (q,k dead)
  u16* P1   = k;
  u16* Q0   = h2;            // FFN2 partials (h2 dead after FFN1)
  u16* wqkv = ws + 5 * TD;
  u16* wob  = wqkv + 3 * MEG;
  u16* w1b  = wob + 1 * MEG;
  u16* w2b  = w1b + 4 * MEG;
  u16* Q1   = w2b + 4 * MEG;  // tail: +8 MB (total ws ~73 MB)

  const dim3 blk(256);

  cvt_all_k<<<12288, blk, 0, stream>>>(wq, wk, wvp, wo, w1, w2, wqkv, wob, w1b, w2b);
  zero_k<<<(4 * MEG + 65536) / 1024, blk, 0, stream>>>(out, l);
  rmsnorm_k<<<M_TOK, blk, 0, stream>>>(x, g1, h);
  gemm_bt_k<4><<<dim3(24, 32), blk, 0, stream>>>(h, wqkv, q, k, vt, 3072, 1024);
  attn_k<<<dim3(40, 32), blk, 0, stream>>>(q, k, vt, out, l);
  norm_o_k<<<M_TOK, blk, 0, stream>>>(out, l, o);
  gemm_sk2_k<<<dim3(8, 32, 2), blk, 0, stream>>>(o, wob, P0, P1, 1024, 1024, 512);    // WO partials
  rmsnorm_wo_k<<<M_TOK, blk, 0, stream>>>(P0, P1, x, g2, out, h2);                    // x2 + h2 fused
  gemm_bt_k<2><<<dim3(32, 32), blk, 0, stream>>>(h2, w1b, t, nullptr, nullptr, 4096, 1024);
  gemm_sk2_k<<<dim3(8, 32, 2), blk, 0, stream>>>(t, w2b, Q0, Q1, 1024, 4096, 2048);   // FFN2 partials
  ffn2_red_k<<<4096, blk, 0, stream>>>(Q0, Q1, out);                                  // out = Q0+Q1+x2
}

// Round 14
// 373.480 us; speedup vs baseline: 1.9882x; 1.0450x over previous
//
#include <hip/hip_runtime.h>
#include <cstdint>

#define B_ 2
#define S_ 2048
#define D_ 1024
#define H_ 16
#define DH_ 64
#define FF_ 4096
#define M_TOK (B_ * S_)  // 4096 token rows

typedef __attribute__((ext_vector_type(8))) short short8;
typedef __attribute__((ext_vector_type(4))) float f32x4;
typedef __attribute__((ext_vector_type(4))) unsigned short us4;

typedef unsigned short u16;

__device__ __forceinline__ float bf2f(u16 u) {
  union { uint32_t u; float f; } x;
  x.u = ((uint32_t)u) << 16;
  return x.f;
}
__device__ __forceinline__ u16 f2bf(float f) {
  union { float f; uint32_t u; } x;
  x.f = f;
  uint32_t r = x.u + 0x7FFFu + ((x.u >> 16) & 1u);  // RNE
  return (u16)(r >> 16);
}

// async global->LDS, 16B per lane: LDS dest = wave-uniform base + lane*16 (m97-verified).
__device__ __forceinline__ void gl_lds16(const void* g, void* l) {
  __builtin_amdgcn_global_load_lds(
      (const __attribute__((address_space(1))) uint32_t*)(uintptr_t)g,
      (__attribute__((address_space(3))) uint32_t*)(uintptr_t)l, 16, 0, 0);
}

// fast gelu (tanh approx): |err| <= ~1e-3, ~14 VALU ops (vs ~30 for erff)
__device__ __forceinline__ float gelu_f(float v) {
  const float y = 0.7978845608f * (v + 0.044715f * v * v * v);
  const float t = exp2f(y * 2.885390082f);  // e^{2y}
  const float th = 1.0f - 2.0f * __builtin_amdgcn_rcpf(t + 1.0f);
  return 0.5f * v * (1.0f + th);
}

// ---------------- fused f32->bf16 weight convert: wqkv(3M) wob(1M) w1b(4M) w2b(4M) ----------------
#define MEG 1048576
__global__ __launch_bounds__(256) void cvt_all_k(const float* __restrict__ wq, const float* __restrict__ wk,
                                                 const float* __restrict__ wv, const float* __restrict__ wo,
                                                 const float* __restrict__ w1, const float* __restrict__ w2,
                                                 u16* __restrict__ wqkv, u16* __restrict__ wob,
                                                 u16* __restrict__ w1b, u16* __restrict__ w2b) {
  const int n = (blockIdx.x * 256 + threadIdx.x) * 4;
  const float* src;
  u16* dst;
  int off;
  if (n < 3 * MEG) {
    dst = wqkv; off = n;
    src = (n < MEG) ? wq + n : (n < 2 * MEG ? wk + (n - MEG) : wv + (n - 2 * MEG));
  } else if (n < 4 * MEG) {
    dst = wob; off = n - 3 * MEG; src = wo + off;
  } else if (n < 8 * MEG) {
    dst = w1b; off = n - 4 * MEG; src = w1 + off;
  } else {
    dst = w2b; off = n - 8 * MEG; src = w2 + off;
  }
  const float4 v = *(const float4*)src;
  us4 o;
  o[0] = f2bf(v.x); o[1] = f2bf(v.y); o[2] = f2bf(v.z); o[3] = f2bf(v.w);
  *(us4*)&dst[off] = o;
}

// ---------------- zero-init: Of (4M f32 in d_out) + l (64K f32) ----------------
__global__ __launch_bounds__(256) void zero_k(float* __restrict__ Of, float* __restrict__ L) {
  const int i = (blockIdx.x * 256 + threadIdx.x) * 4;
  if (i < 4 * MEG) { *(float4*)&Of[i] = float4{0.f, 0.f, 0.f, 0.f}; }
  else { *(float4*)&L[i - 4 * MEG] = float4{0.f, 0.f, 0.f, 0.f}; }
}

// ---------------- normalize: o(bf16) = Of / l ----------------
__global__ __launch_bounds__(256) void norm_o_k(const float* __restrict__ Of, const float* __restrict__ L,
                                                u16* __restrict__ O) {
  const int row = blockIdx.x;  // token
  const int tid = threadIdx.x;
  const int col = tid * 4;
  const int hh = col >> 6;
  const float lv = L[(size_t)((row >> 11) * 16 + hh) * 2048 + (row & 2047)];
  const float inv = 1.0f / lv;
  const float4 v = *(const float4*)&Of[(size_t)row * D_ + col];
  us4 o;
  o[0] = f2bf(v.x * inv); o[1] = f2bf(v.y * inv);
  o[2] = f2bf(v.z * inv); o[3] = f2bf(v.w * inv);
  *(us4*)&O[(size_t)row * D_ + col] = o;
}

// ---------------- RMSNorm (pass 1): f32 in, bf16 out ----------------
__global__ __launch_bounds__(256) void rmsnorm_k(const float* __restrict__ X,
                                                 const float* __restrict__ G,
                                                 u16* __restrict__ Hout) {
  const int row = blockIdx.x;
  const int tid = threadIdx.x;
  const float4 xx = *(const float4*)&X[(size_t)row * D_ + tid * 4];
  float v[4] = {xx.x, xx.y, xx.z, xx.w};
  float s = 0.f;
#pragma unroll
  for (int i = 0; i < 4; ++i) s += v[i] * v[i];
#pragma unroll
  for (int d = 1; d < 64; d <<= 1) s += __shfl_xor(s, d);
  __shared__ float red[4];
  if ((tid & 63) == 0) red[tid >> 6] = s;
  __syncthreads();
  s = red[0] + red[1] + red[2] + red[3];
  const float scale = rsqrtf(s * (1.0f / (float)D_) + 1e-5f);
  const float4 gg = *(const float4*)&G[tid * 4];
  us4 o;
  o[0] = f2bf(v[0] * scale * gg.x);
  o[1] = f2bf(v[1] * scale * gg.y);
  o[2] = f2bf(v[2] * scale * gg.z);
  o[3] = f2bf(v[3] * scale * gg.w);
  *(us4*)&Hout[(size_t)row * D_ + tid * 4] = o;
}

// ---------------- fused WO-reduce + residual + RMSNorm: x2 = P0+P1+x; h2 = rmsnorm(x2)*g2 ----------------
__global__ __launch_bounds__(256) void rmsnorm_wo_k(const u16* __restrict__ P0, const u16* __restrict__ P1,
                                                    const float* __restrict__ X, const float* __restrict__ G,
                                                    float* __restrict__ X2, u16* __restrict__ Hout) {
  const int row = blockIdx.x;
  const int tid = threadIdx.x;
  const size_t off = (size_t)row * D_ + tid * 4;
  const us4 p0 = *(const us4*)&P0[off];
  const us4 p1 = *(const us4*)&P1[off];
  const float4 xx = *(const float4*)&X[off];
  float v[4];
  v[0] = bf2f(p0[0]) + bf2f(p1[0]) + xx.x;
  v[1] = bf2f(p0[1]) + bf2f(p1[1]) + xx.y;
  v[2] = bf2f(p0[2]) + bf2f(p1[2]) + xx.z;
  v[3] = bf2f(p0[3]) + bf2f(p1[3]) + xx.w;
  *(float4*)&X2[off] = float4{v[0], v[1], v[2], v[3]};
  float s = 0.f;
#pragma unroll
  for (int i = 0; i < 4; ++i) s += v[i] * v[i];
#pragma unroll
  for (int d = 1; d < 64; d <<= 1) s += __shfl_xor(s, d);
  __shared__ float red[4];
  if ((tid & 63) == 0) red[tid >> 6] = s;
  __syncthreads();
  s = red[0] + red[1] + red[2] + red[3];
  const float scale = rsqrtf(s * (1.0f / (float)D_) + 1e-5f);
  const float4 gg = *(const float4*)&G[tid * 4];
  us4 o;
  o[0] = f2bf(v[0] * scale * gg.x);
  o[1] = f2bf(v[1] * scale * gg.y);
  o[2] = f2bf(v[2] * scale * gg.z);
  o[3] = f2bf(v[3] * scale * gg.w);
  *(us4*)&Hout[off] = o;
}

// ---------------- FFN2 reduce: out = Q0 + Q1 + x2 (in place on d_out) ----------------
__global__ __launch_bounds__(256) void ffn2_red_k(const u16* __restrict__ Q0, const u16* __restrict__ Q1,
                                                  float* __restrict__ OUT) {
  const int i = (blockIdx.x * 256 + threadIdx.x) * 4;
  const us4 a = *(const us4*)&Q0[i];
  const us4 b = *(const us4*)&Q1[i];
  const float4 c = *(const float4*)&OUT[i];
  *(float4*)&OUT[i] = float4{bf2f(a[0]) + bf2f(b[0]) + c.x, bf2f(a[1]) + bf2f(b[1]) + c.y,
                             bf2f(a[2]) + bf2f(b[2]) + c.z, bf2f(a[3]) + bf2f(b[3]) + c.w};
}

// ---------------- m97-style GEMM with bank-conflict-free XOR swizzle ----------------
// LDS row = 32 u16; store-group sg holds global k-group sg ^ ((row>>1)&3).
// MODE 2: gelu store; MODE 4: QKV scatter.
template <int MODE>
__global__ __launch_bounds__(256) void gemm_bt_k(const u16* __restrict__ A,
                                                 const u16* __restrict__ W,
                                                 u16* __restrict__ C0, u16* __restrict__ C1,
                                                 u16* __restrict__ C2, int N, int K) {
  __shared__ alignas(16) u16 As[128 * 32];
  __shared__ alignas(16) u16 Bs[128 * 32];
  const int tid = threadIdx.x;
  const int wv = tid >> 6, lane = tid & 63;
  const int r = lane & 15, quad = lane >> 4;
  const int bm = blockIdx.y * 128, bn = blockIdx.x * 128;
  const int row0 = (wv >> 1) * 64, col0 = (wv & 1) * 64;

  f32x4 acc[4][4] = {};

  // staging geometry (swizzled source)
  int srow[2], sg[2];
#pragma unroll
  for (int jj = 0; jj < 2; ++jj) {
    const int c = wv * 128 + jj * 64 + lane;
    srow[jj] = c >> 2;
    sg[jj] = (c & 3) ^ ((srow[jj] >> 1) & 3);
  }

  for (int k0 = 0; k0 < K; k0 += 32) {
#pragma unroll
    for (int jj = 0; jj < 2; ++jj) {
      const int l0 = (wv * 128 + jj * 64) * 8;
      gl_lds16(&A[(size_t)(bm + srow[jj]) * K + k0 + sg[jj] * 8], &As[l0]);
      gl_lds16(&W[(size_t)(bn + srow[jj]) * K + k0 + sg[jj] * 8], &Bs[l0]);
    }
    __syncthreads();
    short8 af[4], bf[4];
#pragma unroll
    for (int mt = 0; mt < 4; ++mt) {
      const int mr = row0 + mt * 16 + r;
      af[mt] = *(const short8*)&As[mr * 32 + (quad ^ ((mr >> 1) & 3)) * 8];
    }
#pragma unroll
    for (int nt = 0; nt < 4; ++nt) {
      const int nr = col0 + nt * 16 + r;
      bf[nt] = *(const short8*)&Bs[nr * 32 + (quad ^ ((nr >> 1) & 3)) * 8];
    }
#pragma unroll
    for (int mt = 0; mt < 4; ++mt)
#pragma unroll
      for (int nt = 0; nt < 4; ++nt)
        acc[mt][nt] = __builtin_amdgcn_mfma_f32_16x16x32_bf16(af[mt], bf[nt], acc[mt][nt], 0, 0, 0);
    __syncthreads();
  }

  if constexpr (MODE == 2) {
#pragma unroll
    for (int mt = 0; mt < 4; ++mt)
#pragma unroll
      for (int nt = 0; nt < 4; ++nt)
#pragma unroll
        for (int i = 0; i < 4; ++i) {
          const int grow = bm + row0 + mt * 16 + quad * 4 + i;
          const int gcol = bn + col0 + nt * 16 + r;
          C0[(size_t)grow * N + gcol] = f2bf(gelu_f(acc[mt][nt][i]));
        }
  } else {  // MODE 4: QKV scatter
#pragma unroll
    for (int mt = 0; mt < 4; ++mt) {
      const int grow0 = bm + row0 + mt * 16 + quad * 4;
#pragma unroll
      for (int nt = 0; nt < 4; ++nt) {
        const int gcol = bn + col0 + nt * 16 + r;
        if (gcol < 2048) {
          u16* dst = (gcol < 1024) ? C0 : C1;
          const int cc = gcol & 1023;
#pragma unroll
          for (int i = 0; i < 4; ++i)
            dst[(size_t)(grow0 + i) * 1024 + cc] = f2bf(acc[mt][nt][i]);
        } else {
          const int vcol = gcol - 2048;
          us4 o;
#pragma unroll
          for (int i = 0; i < 4; ++i) o[i] = f2bf(acc[mt][nt][i]);
          const size_t addr =
              ((size_t)((grow0 >> 11) * 16 + (vcol >> 6)) * 64 + (vcol & 63)) * 2048 + (grow0 & 2047);
          *(us4*)&C2[addr] = o;
        }
      }
    }
  }
}

// ---------------- split-K=2 GEMM (swizzled): slice z writes bf16 partial Pz ----------------
__global__ __launch_bounds__(256) void gemm_sk2_k(const u16* __restrict__ A,
                                                  const u16* __restrict__ W,
                                                  u16* __restrict__ P0, u16* __restrict__ P1,
                                                  int N, int K, int KS) {
  __shared__ alignas(16) u16 As[128 * 32];
  __shared__ alignas(16) u16 Bs[128 * 32];
  const int tid = threadIdx.x;
  const int wv = tid >> 6, lane = tid & 63;
  const int r = lane & 15, quad = lane >> 4;
  const int bm = blockIdx.y * 128, bn = blockIdx.x * 128;
  const int row0 = (wv >> 1) * 64, col0 = (wv & 1) * 64;
  const int koff = blockIdx.z * KS;
  u16* P = blockIdx.z ? P1 : P0;

  f32x4 acc[4][4] = {};

  int srow[2], sg[2];
#pragma unroll
  for (int jj = 0; jj < 2; ++jj) {
    const int c = wv * 128 + jj * 64 + lane;
    srow[jj] = c >> 2;
    sg[jj] = (c & 3) ^ ((srow[jj] >> 1) & 3);
  }

  for (int k0 = koff; k0 < koff + KS; k0 += 32) {
#pragma unroll
    for (int jj = 0; jj < 2; ++jj) {
      const int l0 = (wv * 128 + jj * 64) * 8;
      gl_lds16(&A[(size_t)(bm + srow[jj]) * K + k0 + sg[jj] * 8], &As[l0]);
      gl_lds16(&W[(size_t)(bn + srow[jj]) * K + k0 + sg[jj] * 8], &Bs[l0]);
    }
    __syncthreads();
    short8 af[4], bf[4];
#pragma unroll
    for (int mt = 0; mt < 4; ++mt) {
      const int mr = row0 + mt * 16 + r;
      af[mt] = *(const short8*)&As[mr * 32 + (quad ^ ((mr >> 1) & 3)) * 8];
    }
#pragma unroll
    for (int nt = 0; nt < 4; ++nt) {
      const int nr = col0 + nt * 16 + r;
      bf[nt] = *(const short8*)&Bs[nr * 32 + (quad ^ ((nr >> 1) & 3)) * 8];
    }
#pragma unroll
    for (int mt = 0; mt < 4; ++mt)
#pragma unroll
      for (int nt = 0; nt < 4; ++nt)
        acc[mt][nt] = __builtin_amdgcn_mfma_f32_16x16x32_bf16(af[mt], bf[nt], acc[mt][nt], 0, 0, 0);
    __syncthreads();
  }

#pragma unroll
  for (int mt = 0; mt < 4; ++mt)
#pragma unroll
    for (int nt = 0; nt < 4; ++nt)
#pragma unroll
      for (int i = 0; i < 4; ++i) {
        const int grow = bm + row0 + mt * 16 + quad * 4 + i;
        const int gcol = bn + col0 + nt * 16 + r;
        P[(size_t)grow * N + gcol] = f2bf(acc[mt][nt][i]);
      }
}

// ---------------- Flash attention v5 (unchanged from round 13) ----------------
#define SCL 0.18033688011112042f  /* 0.125 * log2(e) */
__global__ __launch_bounds__(256, 2) void attn_k(const u16* __restrict__ Q,
                                                 const u16* __restrict__ Kx,
                                                 const u16* __restrict__ VT,
                                                 float* __restrict__ Of, float* __restrict__ L) {
  __shared__ alignas(16) u16 Ks[2][32 * 72];
  __shared__ alignas(16) u16 Vs[2][64 * 40];
  __shared__ alignas(16) u16 Ps[4][32 * 40];

  const int tid = threadIdx.x;
  const int wv = tid >> 6, lane = tid & 63;
  const int r = lane & 15, quad = lane >> 4;
  const int bh = blockIdx.y;
  const int b = bh >> 4, hh = bh & 15;

  int id = 39 - (int)blockIdx.x;
  int bx = 0;
  for (;;) {
    const int nb = (bx >> 2) + 1;
    if (id < nb) break;
    id -= nb;
    ++bx;
  }
  const int c = id;
  const int j0base = c * 512;
  const int niter = (min(bx * 128 + 128, j0base + 512) - j0base) >> 5;

  const int qbase = bx * 128;
  const int m0 = qbase + wv * 32;
  const size_t base = (size_t)b * S_ * D_ + (size_t)hh * DH_;
  const u16* Qb = Q + base;
  const u16* Kb = Kx + base;
  const u16* VTb = VT + (size_t)bh * 64 * 2048;
  u16* Psw = &Ps[wv][0];

  short8 qf[2][2];
#pragma unroll
  for (int f = 0; f < 2; ++f) {
    qf[f][0] = *(const short8*)&Qb[(size_t)(m0 + f * 16 + r) * D_ + quad * 8];
    qf[f][1] = *(const short8*)&Qb[(size_t)(m0 + f * 16 + r) * D_ + 32 + quad * 8];
  }

  short8 onesv;
#pragma unroll
  for (int e = 0; e < 8; ++e) onesv[e] = (short)0x3F80;

  f32x4 oacc[2][4] = {};
  f32x4 lacc[2] = {};

  const int krow = tid >> 3, kg = tid & 7;
  const int vrow = tid >> 2, vg = tid & 3;

  *(short8*)&Ks[0][krow * 72 + kg * 8] = *(const short8*)&Kb[(size_t)(j0base + krow) * D_ + kg * 8];
  *(short8*)&Vs[0][vrow * 40 + vg * 8] = *(const short8*)&VTb[(size_t)vrow * 2048 + j0base + vg * 8];

  int cur = 0;
  for (int it = 0; it < niter; ++it) {
    const int j0 = j0base + it * 32;
    __syncthreads();

    if (it + 1 < niter) {
      const int j1 = j0 + 32;
      *(short8*)&Ks[cur ^ 1][krow * 72 + kg * 8] =
          *(const short8*)&Kb[(size_t)(j1 + krow) * D_ + kg * 8];
      *(short8*)&Vs[cur ^ 1][vrow * 40 + vg * 8] =
          *(const short8*)&VTb[(size_t)vrow * 2048 + j1 + vg * 8];
    }

    f32x4 z[2][2];
#pragma unroll
    for (int kt = 0; kt < 2; ++kt) {
      const short8 kf0 = *(const short8*)&Ks[cur][(kt * 16 + r) * 72 + quad * 8];
      const short8 kf1 = *(const short8*)&Ks[cur][(kt * 16 + r) * 72 + 32 + quad * 8];
#pragma unroll
      for (int f = 0; f < 2; ++f) {
        f32x4 zz = {};
        zz = __builtin_amdgcn_mfma_f32_16x16x32_bf16(qf[f][0], kf0, zz, 0, 0, 0);
        zz = __builtin_amdgcn_mfma_f32_16x16x32_bf16(qf[f][1], kf1, zz, 0, 0, 0);
        z[f][kt] = zz;
      }
    }

    const bool masked = (j0 + 31 > m0);
#pragma unroll
    for (int f = 0; f < 2; ++f)
#pragma unroll
      for (int i = 0; i < 4; ++i) {
        const int qrow = m0 + f * 16 + quad * 4 + i;
        float v0 = z[f][0][i] * SCL;
        float v1 = z[f][1][i] * SCL;
        if (masked) {
          if (j0 + r > qrow) v0 = -128.f;
          if (j0 + 16 + r > qrow) v1 = -128.f;
        }
        Psw[(f * 16 + quad * 4 + i) * 40 + r] = f2bf(exp2f(v0));
        Psw[(f * 16 + quad * 4 + i) * 40 + 16 + r] = f2bf(exp2f(v1));
      }

    asm volatile("s_waitcnt lgkmcnt(0)" ::: "memory");

    short8 vf[4];
#pragma unroll
    for (int nt = 0; nt < 4; ++nt)
      vf[nt] = *(const short8*)&Vs[cur][(nt * 16 + r) * 40 + quad * 8];
#pragma unroll
    for (int f = 0; f < 2; ++f) {
      const short8 pf = *(const short8*)&Psw[(f * 16 + r) * 40 + quad * 8];
#pragma unroll
      for (int nt = 0; nt < 4; ++nt)
        oacc[f][nt] = __builtin_amdgcn_mfma_f32_16x16x32_bf16(pf, vf[nt], oacc[f][nt], 0, 0, 0);
      lacc[f] = __builtin_amdgcn_mfma_f32_16x16x32_bf16(pf, onesv, lacc[f], 0, 0, 0);
    }

    cur ^= 1;
  }

#pragma unroll
  for (int f = 0; f < 2; ++f) {
#pragma unroll
    for (int i = 0; i < 4; ++i) {
      const int qrow = m0 + f * 16 + quad * 4 + i;
#pragma unroll
      for (int nt = 0; nt < 4; ++nt)
        atomicAdd(&Of[base + (size_t)qrow * D_ + nt * 16 + r], oacc[f][nt][i]);
      if (r == 0) atomicAdd(&L[(size_t)bh * 2048 + qrow], lacc[f][i]);
    }
  }
}

extern "C" void kernel_launch(void* const* d_in, const int* in_sizes, int n_in,
                              void* d_out, int out_size, void* d_ws, size_t ws_size,
                              hipStream_t stream) {
  (void)in_sizes; (void)n_in; (void)out_size; (void)ws_size;
  const float* x   = (const float*)d_in[0];
  const float* wq  = (const float*)d_in[1];
  const float* wk  = (const float*)d_in[2];
  const float* wvp = (const float*)d_in[3];
  const float* wo  = (const float*)d_in[4];
  const float* w1  = (const float*)d_in[5];
  const float* w2  = (const float*)d_in[6];
  const float* g1  = (const float*)d_in[7];
  const float* g2  = (const float*)d_in[8];
  float* out = (float*)d_out;  // Of accumulator -> x2 -> final output

  u16* ws = (u16*)d_ws;
  const size_t TD = (size_t)M_TOK * D_;  // 4M elems (8 MB)
  u16* h    = ws;            // slot0: h -> o -> t[0]
  u16* q    = ws + 1 * TD;   // slot1: q -> P0 -> t[1]
  u16* k    = ws + 2 * TD;   // slot2: k -> P1 -> t[2]
  u16* vt   = ws + 3 * TD;   // slot3: vt -> t[3]
  u16* h2   = ws + 4 * TD;   // slot4: l (head) -> h2 -> Q0
  float* l  = (float*)(ws + 4 * TD);
  u16* o    = h;
  u16* t    = ws;            // FFN1 out spans slots 0..3
  u16* P0   = q;             // WO partials (q,k dead)
  u16* P1   = k;
  u16* Q0   = h2;            // FFN2 partials (h2 dead after FFN1)
  u16* wqkv = ws + 5 * TD;
  u16* wob  = wqkv + 3 * MEG;
  u16* w1b  = wob + 1 * MEG;
  u16* w2b  = w1b + 4 * MEG;
  u16* Q1   = w2b + 4 * MEG;  // tail: +8 MB (total ws ~73 MB)

  const dim3 blk(256);

  cvt_all_k<<<12288, blk, 0, stream>>>(wq, wk, wvp, wo, w1, w2, wqkv, wob, w1b, w2b);
  zero_k<<<(4 * MEG + 65536) / 1024, blk, 0, stream>>>(out, l);
  rmsnorm_k<<<M_TOK, blk, 0, stream>>>(x, g1, h);
  gemm_bt_k<4><<<dim3(24, 32), blk, 0, stream>>>(h, wqkv, q, k, vt, 3072, 1024);
  attn_k<<<dim3(40, 32), blk, 0, stream>>>(q, k, vt, out, l);
  norm_o_k<<<M_TOK, blk, 0, stream>>>(out, l, o);
  gemm_sk2_k<<<dim3(8, 32, 2), blk, 0, stream>>>(o, wob, P0, P1, 1024, 1024, 512);    // WO partials
  rmsnorm_wo_k<<<M_TOK, blk, 0, stream>>>(P0, P1, x, g2, out, h2);                    // x2 + h2 fused
  gemm_bt_k<2><<<dim3(32, 32), blk, 0, stream>>>(h2, w1b, t, nullptr, nullptr, 4096, 1024);
  gemm_sk2_k<<<dim3(8, 32, 2), blk, 0, stream>>>(t, w2b, Q0, Q1, 1024, 4096, 2048);   // FFN2 partials
  ffn2_red_k<<<4096, blk, 0, stream>>>(Q0, Q1, out);                                  // out = Q0+Q1+x2
}